// Round 1
// baseline (723.798 us; speedup 1.0000x reference)
//
#include <hip/hip_runtime.h>

#define F 128
#define GRAPHS 64
#define GN_EPS 1e-5f
#define SCAN_B 256

// ---------------- degree + per-node edge count ----------------
__global__ void deg_kernel(const int* __restrict__ ei, const float* __restrict__ w,
                           float* __restrict__ deg, int* __restrict__ cnt, int E) {
    int e = blockIdx.x * blockDim.x + threadIdx.x;
    if (e >= E) return;
    int dst = ei[E + e];
    atomicAdd(&deg[dst], w[e]);
    atomicAdd(&cnt[dst], 1);
}

// ---------------- dinv + per-graph node count ----------------
__global__ void dinv_gcnt_kernel(const float* __restrict__ deg, float* __restrict__ dinv,
                                 const int* __restrict__ batch, int* __restrict__ gcnt, int n) {
    int i = blockIdx.x * blockDim.x + threadIdx.x;
    if (i >= n) return;
    float d = deg[i];
    dinv[i] = (d > 0.f) ? rsqrtf(fmaxf(d, 1e-30f)) : 0.f;
    atomicAdd(&gcnt[batch[i]], 1);
}

// ---------------- exclusive scan of cnt -> offsets (3 phases) ----------------
__global__ void scan1_kernel(const int* __restrict__ cnt, int* __restrict__ excl,
                             int* __restrict__ blockSums, int n) {
    __shared__ int s[SCAN_B];
    int i = blockIdx.x * SCAN_B + threadIdx.x;
    int v = (i < n) ? cnt[i] : 0;
    s[threadIdx.x] = v;
    __syncthreads();
    for (int off = 1; off < SCAN_B; off <<= 1) {
        int t = (threadIdx.x >= off) ? s[threadIdx.x - off] : 0;
        __syncthreads();
        s[threadIdx.x] += t;
        __syncthreads();
    }
    if (i < n) excl[i] = s[threadIdx.x] - v;      // exclusive within block
    if (threadIdx.x == SCAN_B - 1) blockSums[blockIdx.x] = s[SCAN_B - 1];
}

__global__ void scan2_kernel(int* __restrict__ blockSums, int nb) {
    __shared__ int s[1024];
    int v = (threadIdx.x < nb) ? blockSums[threadIdx.x] : 0;
    s[threadIdx.x] = v;
    __syncthreads();
    for (int off = 1; off < 1024; off <<= 1) {
        int t = (threadIdx.x >= off) ? s[threadIdx.x - off] : 0;
        __syncthreads();
        s[threadIdx.x] += t;
        __syncthreads();
    }
    if (threadIdx.x < nb) blockSums[threadIdx.x] = s[threadIdx.x] - v;  // exclusive
}

__global__ void scan3_kernel(int* __restrict__ offs, const int* __restrict__ blockSums,
                             int* __restrict__ cur, int n, int total) {
    int i = blockIdx.x * SCAN_B + threadIdx.x;
    if (i < n) {
        int o = offs[i] + blockSums[blockIdx.x];
        offs[i] = o;
        cur[i] = o;
    }
    if (i == 0) offs[n] = total;
}

// ---------------- scatter edges into CSR (by dst), fuse norm computation ----------------
__global__ void scatter_kernel(const int* __restrict__ ei, const float* __restrict__ w,
                               const float* __restrict__ dinv, int* __restrict__ cur,
                               int* __restrict__ csr_src, float* __restrict__ csr_norm, int E) {
    int e = blockIdx.x * blockDim.x + threadIdx.x;
    if (e >= E) return;
    int s = ei[e];
    int d = ei[E + e];
    int p = atomicAdd(&cur[d], 1);
    csr_src[p] = s;
    csr_norm[p] = dinv[s] * w[e] * dinv[d];
}

// ---------------- one hop: hout[n] = sum_e norm[e] * hin[src[e]]  (gather form) ----------------
__global__ __launch_bounds__(256) void hop_kernel(const float4* __restrict__ hin,
                                                  float4* __restrict__ hout,
                                                  const int* __restrict__ offs,
                                                  const int* __restrict__ csr_src,
                                                  const float* __restrict__ csr_norm, int n) {
    int lane = threadIdx.x & 31;                       // 32 lanes * float4 = 128 feats
    int node = blockIdx.x * (blockDim.x >> 5) + (threadIdx.x >> 5);
    if (node >= n) return;
    int e0 = offs[node], e1 = offs[node + 1];
    float4 acc = make_float4(0.f, 0.f, 0.f, 0.f);
    for (int e = e0; e < e1; ++e) {
        int s = csr_src[e];
        float wv = csr_norm[e];
        float4 hv = hin[s * 32 + lane];
        acc.x += wv * hv.x; acc.y += wv * hv.y;
        acc.z += wv * hv.z; acc.w += wv * hv.w;
    }
    hout[node * 32 + lane] = acc;
}

// ---------------- out[M,128] (+)= A[M,128] @ W[128,128] (+bias) : fp32 VALU ----------------
#define MM_BM 64
__global__ __launch_bounds__(256) void matmul_kernel(const float* __restrict__ A,
                                                     const float* __restrict__ W,
                                                     float* __restrict__ out,
                                                     const float* __restrict__ bias,
                                                     int M, int addTo, int addBias) {
    __shared__ float Bs[32][128];        // 16 KB
    __shared__ float At[32][MM_BM + 4];  // transposed A tile, padded stride 68 (16B aligned)
    int tid = threadIdx.x;
    int tx = tid & 31;    // col group: cols tx*4..tx*4+3
    int ty = tid >> 5;    // row group: rows ty*8..ty*8+7
    int row0 = blockIdx.x * MM_BM;
    float acc[8][4] = {};

    for (int k0 = 0; k0 < 128; k0 += 32) {
        // stage B tile 32x128
        #pragma unroll
        for (int it = 0; it < 4; ++it) {
            int idx = tid + it * 256;      // float4 index 0..1023
            int kk = idx >> 5;
            int cc = (idx & 31) << 2;
            *(float4*)&Bs[kk][cc] = *(const float4*)&W[(size_t)(k0 + kk) * 128 + cc];
        }
        // stage A tile transposed: 64 rows x 32 k
        #pragma unroll
        for (int it = 0; it < 2; ++it) {
            int idx = tid + it * 256;      // 0..511
            int r = idx >> 3;              // 0..63
            int kq = (idx & 7) << 2;       // 0,4,...,28
            int nrow = row0 + r;
            float4 a = (nrow < M) ? *(const float4*)&A[(size_t)nrow * 128 + k0 + kq]
                                  : make_float4(0.f, 0.f, 0.f, 0.f);
            At[kq + 0][r] = a.x; At[kq + 1][r] = a.y;
            At[kq + 2][r] = a.z; At[kq + 3][r] = a.w;
        }
        __syncthreads();

        #pragma unroll 4
        for (int k = 0; k < 32; ++k) {
            float4 b = *(float4*)&Bs[k][tx << 2];
            float4 a0 = *(float4*)&At[k][ty * 8];
            float4 a1 = *(float4*)&At[k][ty * 8 + 4];
            float ar[8] = {a0.x, a0.y, a0.z, a0.w, a1.x, a1.y, a1.z, a1.w};
            #pragma unroll
            for (int r = 0; r < 8; ++r) {
                acc[r][0] += ar[r] * b.x;
                acc[r][1] += ar[r] * b.y;
                acc[r][2] += ar[r] * b.z;
                acc[r][3] += ar[r] * b.w;
            }
        }
        __syncthreads();
    }

    #pragma unroll
    for (int r = 0; r < 8; ++r) {
        int nrow = row0 + ty * 8 + r;
        if (nrow < M) {
            float* po = &out[(size_t)nrow * 128 + (tx << 2)];
            float4 o = make_float4(acc[r][0], acc[r][1], acc[r][2], acc[r][3]);
            if (addBias) {
                float4 bb = *(const float4*)&bias[tx << 2];
                o.x += bb.x; o.y += bb.y; o.z += bb.z; o.w += bb.w;
            }
            if (addTo) {
                float4 prev = *(float4*)po;
                o.x += prev.x; o.y += prev.y; o.z += prev.z; o.w += prev.w;
            }
            *(float4*)po = o;
        }
    }
}

// ---------------- per-graph sums S1, S2 (batch sorted -> flush on change) ----------------
#define STAT_NODES 256
__global__ __launch_bounds__(128) void stats_kernel(const float* __restrict__ out,
                                                    const int* __restrict__ batch,
                                                    float* __restrict__ S1, float* __restrict__ S2,
                                                    int n) {
    int f = threadIdx.x;  // 0..127
    int n0 = blockIdx.x * STAT_NODES;
    int n1 = min(n0 + STAT_NODES, n);
    float s1 = 0.f, s2 = 0.f;
    int curg = batch[n0];
    for (int i = n0; i < n1; ++i) {
        int g = batch[i];
        if (g != curg) {
            atomicAdd(&S1[curg * F + f], s1);
            atomicAdd(&S2[curg * F + f], s2);
            s1 = 0.f; s2 = 0.f; curg = g;
        }
        float v = out[(size_t)i * F + f];
        s1 += v; s2 += v * v;
    }
    atomicAdd(&S1[curg * F + f], s1);
    atomicAdd(&S2[curg * F + f], s2);
}

// ---------------- finalize mean/var -> sm = s*mean, Ag = gnw * rsqrt(var+eps) ----------------
__global__ void finalize_kernel(const float* __restrict__ S1, const float* __restrict__ S2,
                                const int* __restrict__ gcnt, const float* __restrict__ gnw,
                                const float* __restrict__ gms,
                                float* __restrict__ sm, float* __restrict__ Ag, int GF) {
    int i = blockIdx.x * blockDim.x + threadIdx.x;
    if (i >= GF) return;
    int f = i & (F - 1);
    int g = i >> 7;
    float c = fmaxf((float)gcnt[g], 1.f);
    float mean = S1[i] / c;
    float e2 = S2[i] / c;
    float s = gms[f];
    float var = e2 - 2.f * s * mean * mean + s * s * mean * mean;
    sm[i] = s * mean;
    Ag[i] = gnw[f] * rsqrtf(var + GN_EPS);
}

// ---------------- fused normalize + relu + residual ----------------
__global__ void final_kernel(const float4* __restrict__ y, const float4* __restrict__ out,
                             const int* __restrict__ batch, const float4* __restrict__ sm,
                             const float4* __restrict__ Ag, const float4* __restrict__ gnb,
                             float4* __restrict__ res, int n) {
    int idx = blockIdx.x * blockDim.x + threadIdx.x;  // over n*32 float4s
    if (idx >= n * 32) return;
    int node = idx >> 5;
    int q = idx & 31;
    int g = batch[node];
    float4 o = out[idx];
    float4 yv = y[idx];
    float4 m = sm[g * 32 + q];
    float4 a = Ag[g * 32 + q];
    float4 b = gnb[q];
    float4 r;
    r.x = yv.x + fmaxf(0.f, (o.x - m.x) * a.x + b.x);
    r.y = yv.y + fmaxf(0.f, (o.y - m.y) * a.y + b.y);
    r.z = yv.z + fmaxf(0.f, (o.z - m.z) * a.z + b.z);
    r.w = yv.w + fmaxf(0.f, (o.w - m.w) * a.w + b.w);
    res[idx] = r;
}

extern "C" void kernel_launch(void* const* d_in, const int* in_sizes, int n_in,
                              void* d_out, int out_size, void* d_ws, size_t ws_size,
                              hipStream_t stream) {
    const float* y     = (const float*)d_in[0];
    const int*   ei    = (const int*)d_in[1];
    const float* ew    = (const float*)d_in[2];
    const int*   batch = (const int*)d_in[3];
    const float* tag_w = (const float*)d_in[4];
    const float* tag_b = (const float*)d_in[5];
    const float* gnw   = (const float*)d_in[6];
    const float* gnb   = (const float*)d_in[7];
    const float* gms   = (const float*)d_in[8];
    float* res = (float*)d_out;

    const int N = in_sizes[0] / F;
    const int E = in_sizes[1] / 2;

    // ---- workspace layout (zero-init region first, one memset) ----
    char* p = (char*)d_ws;
    float* deg = (float*)p;      p += (size_t)N * 4;
    int*   cnt = (int*)p;        p += (size_t)N * 4;
    int*   gcnt = (int*)p;       p += 256;
    float* S1 = (float*)p;       p += (size_t)GRAPHS * F * 4;
    float* S2 = (float*)p;       p += (size_t)GRAPHS * F * 4;
    size_t zeroBytes = (size_t)(p - (char*)d_ws);
    float* dinv = (float*)p;     p += (size_t)N * 4;
    int*   offs = (int*)p;       p += (size_t)(N + 4) * 4;
    int*   cur = (int*)p;        p += (size_t)N * 4;
    int*   blockSums = (int*)p;  p += 4096;
    int*   csr_src = (int*)p;    p += (size_t)E * 4;
    float* csr_norm = (float*)p; p += (size_t)E * 4;
    float* sm = (float*)p;       p += (size_t)GRAPHS * F * 4;
    float* Ag = (float*)p;       p += (size_t)GRAPHS * F * 4;
    float* h1 = (float*)p;       p += (size_t)N * F * 4;
    float* h2 = (float*)p;       p += (size_t)N * F * 4;
    float* outb = (float*)p;     p += (size_t)N * F * 4;

    hipMemsetAsync(d_ws, 0, zeroBytes, stream);

    int eb = (E + 255) / 256;
    int nb = (N + 255) / 256;
    int sb = (N + SCAN_B - 1) / SCAN_B;

    deg_kernel<<<eb, 256, 0, stream>>>(ei, ew, deg, cnt, E);
    dinv_gcnt_kernel<<<nb, 256, 0, stream>>>(deg, dinv, batch, gcnt, N);
    scan1_kernel<<<sb, SCAN_B, 0, stream>>>(cnt, offs, blockSums, N);
    scan2_kernel<<<1, 1024, 0, stream>>>(blockSums, sb);
    scan3_kernel<<<sb, SCAN_B, 0, stream>>>(offs, blockSums, cur, N, E);
    scatter_kernel<<<eb, 256, 0, stream>>>(ei, ew, dinv, cur, csr_src, csr_norm, E);

    int mb = (N + MM_BM - 1) / MM_BM;
    int hb = (N + 7) / 8;
    matmul_kernel<<<mb, 256, 0, stream>>>(y, tag_w + 0 * F * F, outb, tag_b, N, 0, 0);
    hop_kernel<<<hb, 256, 0, stream>>>((const float4*)y, (float4*)h1, offs, csr_src, csr_norm, N);
    matmul_kernel<<<mb, 256, 0, stream>>>(h1, tag_w + 1 * F * F, outb, tag_b, N, 1, 0);
    hop_kernel<<<hb, 256, 0, stream>>>((const float4*)h1, (float4*)h2, offs, csr_src, csr_norm, N);
    matmul_kernel<<<mb, 256, 0, stream>>>(h2, tag_w + 2 * F * F, outb, tag_b, N, 1, 0);
    hop_kernel<<<hb, 256, 0, stream>>>((const float4*)h2, (float4*)h1, offs, csr_src, csr_norm, N);
    matmul_kernel<<<mb, 256, 0, stream>>>(h1, tag_w + 3 * F * F, outb, tag_b, N, 1, 1);

    stats_kernel<<<(N + STAT_NODES - 1) / STAT_NODES, 128, 0, stream>>>(outb, batch, S1, S2, N);
    finalize_kernel<<<(GRAPHS * F + 255) / 256, 256, 0, stream>>>(S1, S2, gcnt, gnw, gms, sm, Ag, GRAPHS * F);
    final_kernel<<<(N * 32 + 255) / 256, 256, 0, stream>>>((const float4*)y, (const float4*)outb,
                                                           batch, (const float4*)sm, (const float4*)Ag,
                                                           (const float4*)gnb, (float4*)res, N);
}

// Round 2
// 580.420 us; speedup vs baseline: 1.2470x; 1.2470x over previous
//
#include <hip/hip_runtime.h>

#define F 128
#define GRAPHS 64
#define GN_EPS 1e-5f
#define SCAN_B 256

// ---------------- degree + per-node edge count ----------------
__global__ void deg_kernel(const int* __restrict__ ei, const float* __restrict__ w,
                           float* __restrict__ deg, int* __restrict__ cnt, int E) {
    int e = blockIdx.x * blockDim.x + threadIdx.x;
    if (e >= E) return;
    int dst = ei[E + e];
    atomicAdd(&deg[dst], w[e]);
    atomicAdd(&cnt[dst], 1);
}

// ---------------- dinv + graph segment boundaries (batch is SORTED -> no atomics) --------
__global__ void dinv_start_kernel(const float* __restrict__ deg, float* __restrict__ dinv,
                                  const int* __restrict__ batch, int* __restrict__ gstart, int n) {
    int i = blockIdx.x * blockDim.x + threadIdx.x;
    if (i >= n) return;
    float d = deg[i];
    dinv[i] = (d > 0.f) ? rsqrtf(fmaxf(d, 1e-30f)) : 0.f;
    int b = batch[i];
    if (i == 0) {
        for (int g = 0; g <= b; ++g) gstart[g] = 0;
    } else {
        int bp = batch[i - 1];
        for (int g = bp + 1; g <= b; ++g) gstart[g] = i;
    }
    if (i == n - 1) {
        for (int g = b + 1; g <= GRAPHS; ++g) gstart[g] = n;
    }
}

// ---------------- exclusive scan of cnt -> offsets (3 phases) ----------------
__global__ void scan1_kernel(const int* __restrict__ cnt, int* __restrict__ excl,
                             int* __restrict__ blockSums, int n) {
    __shared__ int s[SCAN_B];
    int i = blockIdx.x * SCAN_B + threadIdx.x;
    int v = (i < n) ? cnt[i] : 0;
    s[threadIdx.x] = v;
    __syncthreads();
    for (int off = 1; off < SCAN_B; off <<= 1) {
        int t = (threadIdx.x >= off) ? s[threadIdx.x - off] : 0;
        __syncthreads();
        s[threadIdx.x] += t;
        __syncthreads();
    }
    if (i < n) excl[i] = s[threadIdx.x] - v;      // exclusive within block
    if (threadIdx.x == SCAN_B - 1) blockSums[blockIdx.x] = s[SCAN_B - 1];
}

__global__ void scan2_kernel(int* __restrict__ blockSums, int nb) {
    __shared__ int s[1024];
    int v = (threadIdx.x < nb) ? blockSums[threadIdx.x] : 0;
    s[threadIdx.x] = v;
    __syncthreads();
    for (int off = 1; off < 1024; off <<= 1) {
        int t = (threadIdx.x >= off) ? s[threadIdx.x - off] : 0;
        __syncthreads();
        s[threadIdx.x] += t;
        __syncthreads();
    }
    if (threadIdx.x < nb) blockSums[threadIdx.x] = s[threadIdx.x] - v;  // exclusive
}

__global__ void scan3_kernel(int* __restrict__ offs, const int* __restrict__ blockSums,
                             int* __restrict__ cur, int n, int total) {
    int i = blockIdx.x * SCAN_B + threadIdx.x;
    if (i < n) {
        int o = offs[i] + blockSums[blockIdx.x];
        offs[i] = o;
        cur[i] = o;
    }
    if (i == 0) offs[n] = total;
}

// ---------------- scatter edges into CSR (by dst), fuse norm computation ----------------
__global__ void scatter_kernel(const int* __restrict__ ei, const float* __restrict__ w,
                               const float* __restrict__ dinv, int* __restrict__ cur,
                               int* __restrict__ csr_src, float* __restrict__ csr_norm, int E) {
    int e = blockIdx.x * blockDim.x + threadIdx.x;
    if (e >= E) return;
    int s = ei[e];
    int d = ei[E + e];
    int p = atomicAdd(&cur[d], 1);
    csr_src[p] = s;
    csr_norm[p] = dinv[s] * w[e] * dinv[d];
}

// ---------------- one hop: hout[n] = sum_e norm[e] * hin[src[e]]  (gather form) ----------------
__global__ __launch_bounds__(256) void hop_kernel(const float4* __restrict__ hin,
                                                  float4* __restrict__ hout,
                                                  const int* __restrict__ offs,
                                                  const int* __restrict__ csr_src,
                                                  const float* __restrict__ csr_norm, int n) {
    int lane = threadIdx.x & 31;                       // 32 lanes * float4 = 128 feats
    int node = blockIdx.x * (blockDim.x >> 5) + (threadIdx.x >> 5);
    if (node >= n) return;
    int e0 = offs[node], e1 = offs[node + 1];
    float4 acc = make_float4(0.f, 0.f, 0.f, 0.f);
    for (int e = e0; e < e1; ++e) {
        int s = csr_src[e];
        float wv = csr_norm[e];
        float4 hv = hin[s * 32 + lane];
        acc.x += wv * hv.x; acc.y += wv * hv.y;
        acc.z += wv * hv.z; acc.w += wv * hv.w;
    }
    hout[node * 32 + lane] = acc;
}

// ---------------- out[M,128] (+)= A[M,128] @ W[128,128] (+bias) : fp32 VALU ----------------
#define MM_BM 64
__global__ __launch_bounds__(256) void matmul_kernel(const float* __restrict__ A,
                                                     const float* __restrict__ W,
                                                     float* __restrict__ out,
                                                     const float* __restrict__ bias,
                                                     int M, int addTo, int addBias) {
    __shared__ float Bs[32][128];        // 16 KB
    __shared__ float At[32][MM_BM + 4];  // transposed A tile, padded stride 68 (16B aligned)
    int tid = threadIdx.x;
    int tx = tid & 31;    // col group: cols tx*4..tx*4+3
    int ty = tid >> 5;    // row group: rows ty*8..ty*8+7
    int row0 = blockIdx.x * MM_BM;
    float acc[8][4] = {};

    for (int k0 = 0; k0 < 128; k0 += 32) {
        // stage B tile 32x128
        #pragma unroll
        for (int it = 0; it < 4; ++it) {
            int idx = tid + it * 256;      // float4 index 0..1023
            int kk = idx >> 5;
            int cc = (idx & 31) << 2;
            *(float4*)&Bs[kk][cc] = *(const float4*)&W[(size_t)(k0 + kk) * 128 + cc];
        }
        // stage A tile transposed: 64 rows x 32 k
        #pragma unroll
        for (int it = 0; it < 2; ++it) {
            int idx = tid + it * 256;      // 0..511
            int r = idx >> 3;              // 0..63
            int kq = (idx & 7) << 2;       // 0,4,...,28
            int nrow = row0 + r;
            float4 a = (nrow < M) ? *(const float4*)&A[(size_t)nrow * 128 + k0 + kq]
                                  : make_float4(0.f, 0.f, 0.f, 0.f);
            At[kq + 0][r] = a.x; At[kq + 1][r] = a.y;
            At[kq + 2][r] = a.z; At[kq + 3][r] = a.w;
        }
        __syncthreads();

        #pragma unroll 4
        for (int k = 0; k < 32; ++k) {
            float4 b = *(float4*)&Bs[k][tx << 2];
            float4 a0 = *(float4*)&At[k][ty * 8];
            float4 a1 = *(float4*)&At[k][ty * 8 + 4];
            float ar[8] = {a0.x, a0.y, a0.z, a0.w, a1.x, a1.y, a1.z, a1.w};
            #pragma unroll
            for (int r = 0; r < 8; ++r) {
                acc[r][0] += ar[r] * b.x;
                acc[r][1] += ar[r] * b.y;
                acc[r][2] += ar[r] * b.z;
                acc[r][3] += ar[r] * b.w;
            }
        }
        __syncthreads();
    }

    #pragma unroll
    for (int r = 0; r < 8; ++r) {
        int nrow = row0 + ty * 8 + r;
        if (nrow < M) {
            float* po = &out[(size_t)nrow * 128 + (tx << 2)];
            float4 o = make_float4(acc[r][0], acc[r][1], acc[r][2], acc[r][3]);
            if (addBias) {
                float4 bb = *(const float4*)&bias[tx << 2];
                o.x += bb.x; o.y += bb.y; o.z += bb.z; o.w += bb.w;
            }
            if (addTo) {
                float4 prev = *(float4*)po;
                o.x += prev.x; o.y += prev.y; o.z += prev.z; o.w += prev.w;
            }
            *(float4*)po = o;
        }
    }
}

// ---------------- per-graph sums S1, S2 (batch sorted -> flush on change) ----------------
#define STAT_NODES 256
__global__ __launch_bounds__(128) void stats_kernel(const float* __restrict__ out,
                                                    const int* __restrict__ batch,
                                                    float* __restrict__ S1, float* __restrict__ S2,
                                                    int n) {
    int f = threadIdx.x;  // 0..127
    int n0 = blockIdx.x * STAT_NODES;
    int n1 = min(n0 + STAT_NODES, n);
    float s1 = 0.f, s2 = 0.f;
    int curg = batch[n0];
    for (int i = n0; i < n1; ++i) {
        int g = batch[i];
        if (g != curg) {
            atomicAdd(&S1[curg * F + f], s1);
            atomicAdd(&S2[curg * F + f], s2);
            s1 = 0.f; s2 = 0.f; curg = g;
        }
        float v = out[(size_t)i * F + f];
        s1 += v; s2 += v * v;
    }
    atomicAdd(&S1[curg * F + f], s1);
    atomicAdd(&S2[curg * F + f], s2);
}

// ---------------- finalize mean/var -> sm = s*mean, Ag = gnw * rsqrt(var+eps) ----------------
__global__ void finalize_kernel(const float* __restrict__ S1, const float* __restrict__ S2,
                                const int* __restrict__ gstart, const float* __restrict__ gnw,
                                const float* __restrict__ gms,
                                float* __restrict__ sm, float* __restrict__ Ag, int GF) {
    int i = blockIdx.x * blockDim.x + threadIdx.x;
    if (i >= GF) return;
    int f = i & (F - 1);
    int g = i >> 7;
    float c = fmaxf((float)(gstart[g + 1] - gstart[g]), 1.f);
    float mean = S1[i] / c;
    float e2 = S2[i] / c;
    float s = gms[f];
    float var = e2 - 2.f * s * mean * mean + s * s * mean * mean;
    sm[i] = s * mean;
    Ag[i] = gnw[f] * rsqrtf(var + GN_EPS);
}

// ---------------- fused normalize + relu + residual ----------------
__global__ void final_kernel(const float4* __restrict__ y, const float4* __restrict__ out,
                             const int* __restrict__ batch, const float4* __restrict__ sm,
                             const float4* __restrict__ Ag, const float4* __restrict__ gnb,
                             float4* __restrict__ res, int n) {
    int idx = blockIdx.x * blockDim.x + threadIdx.x;  // over n*32 float4s
    if (idx >= n * 32) return;
    int node = idx >> 5;
    int q = idx & 31;
    int g = batch[node];
    float4 o = out[idx];
    float4 yv = y[idx];
    float4 m = sm[g * 32 + q];
    float4 a = Ag[g * 32 + q];
    float4 b = gnb[q];
    float4 r;
    r.x = yv.x + fmaxf(0.f, (o.x - m.x) * a.x + b.x);
    r.y = yv.y + fmaxf(0.f, (o.y - m.y) * a.y + b.y);
    r.z = yv.z + fmaxf(0.f, (o.z - m.z) * a.z + b.z);
    r.w = yv.w + fmaxf(0.f, (o.w - m.w) * a.w + b.w);
    res[idx] = r;
}

extern "C" void kernel_launch(void* const* d_in, const int* in_sizes, int n_in,
                              void* d_out, int out_size, void* d_ws, size_t ws_size,
                              hipStream_t stream) {
    const float* y     = (const float*)d_in[0];
    const int*   ei    = (const int*)d_in[1];
    const float* ew    = (const float*)d_in[2];
    const int*   batch = (const int*)d_in[3];
    const float* tag_w = (const float*)d_in[4];
    const float* tag_b = (const float*)d_in[5];
    const float* gnw   = (const float*)d_in[6];
    const float* gnb   = (const float*)d_in[7];
    const float* gms   = (const float*)d_in[8];
    float* res = (float*)d_out;

    const int N = in_sizes[0] / F;
    const int E = in_sizes[1] / 2;

    // ---- workspace layout (zero-init region first, one memset) ----
    char* p = (char*)d_ws;
    float* deg = (float*)p;      p += (size_t)N * 4;
    int*   cnt = (int*)p;        p += (size_t)N * 4;
    float* S1 = (float*)p;       p += (size_t)GRAPHS * F * 4;
    float* S2 = (float*)p;       p += (size_t)GRAPHS * F * 4;
    size_t zeroBytes = (size_t)(p - (char*)d_ws);
    int*   gstart = (int*)p;     p += 512;               // GRAPHS+1 ints (no zeroing needed)
    float* dinv = (float*)p;     p += (size_t)N * 4;
    int*   offs = (int*)p;       p += (size_t)(N + 4) * 4;
    int*   cur = (int*)p;        p += (size_t)N * 4;
    int*   blockSums = (int*)p;  p += 4096;
    int*   csr_src = (int*)p;    p += (size_t)E * 4;
    float* csr_norm = (float*)p; p += (size_t)E * 4;
    float* sm = (float*)p;       p += (size_t)GRAPHS * F * 4;
    float* Ag = (float*)p;       p += (size_t)GRAPHS * F * 4;
    float* h1 = (float*)p;       p += (size_t)N * F * 4;
    float* h2 = (float*)p;       p += (size_t)N * F * 4;
    float* outb = (float*)p;     p += (size_t)N * F * 4;

    hipMemsetAsync(d_ws, 0, zeroBytes, stream);

    int eb = (E + 255) / 256;
    int nb = (N + 255) / 256;
    int sb = (N + SCAN_B - 1) / SCAN_B;

    deg_kernel<<<eb, 256, 0, stream>>>(ei, ew, deg, cnt, E);
    dinv_start_kernel<<<nb, 256, 0, stream>>>(deg, dinv, batch, gstart, N);
    scan1_kernel<<<sb, SCAN_B, 0, stream>>>(cnt, offs, blockSums, N);
    scan2_kernel<<<1, 1024, 0, stream>>>(blockSums, sb);
    scan3_kernel<<<sb, SCAN_B, 0, stream>>>(offs, blockSums, cur, N, E);
    scatter_kernel<<<eb, 256, 0, stream>>>(ei, ew, dinv, cur, csr_src, csr_norm, E);

    int mb = (N + MM_BM - 1) / MM_BM;
    int hb = (N + 7) / 8;
    matmul_kernel<<<mb, 256, 0, stream>>>(y, tag_w + 0 * F * F, outb, tag_b, N, 0, 0);
    hop_kernel<<<hb, 256, 0, stream>>>((const float4*)y, (float4*)h1, offs, csr_src, csr_norm, N);
    matmul_kernel<<<mb, 256, 0, stream>>>(h1, tag_w + 1 * F * F, outb, tag_b, N, 1, 0);
    hop_kernel<<<hb, 256, 0, stream>>>((const float4*)h1, (float4*)h2, offs, csr_src, csr_norm, N);
    matmul_kernel<<<mb, 256, 0, stream>>>(h2, tag_w + 2 * F * F, outb, tag_b, N, 1, 0);
    hop_kernel<<<hb, 256, 0, stream>>>((const float4*)h2, (float4*)h1, offs, csr_src, csr_norm, N);
    matmul_kernel<<<mb, 256, 0, stream>>>(h1, tag_w + 3 * F * F, outb, tag_b, N, 1, 1);

    stats_kernel<<<(N + STAT_NODES - 1) / STAT_NODES, 128, 0, stream>>>(outb, batch, S1, S2, N);
    finalize_kernel<<<(GRAPHS * F + 255) / 256, 256, 0, stream>>>(S1, S2, gstart, gnw, gms, sm, Ag, GRAPHS * F);
    final_kernel<<<(N * 32 + 255) / 256, 256, 0, stream>>>((const float4*)y, (const float4*)outb,
                                                           batch, (const float4*)sm, (const float4*)Ag,
                                                           (const float4*)gnb, (float4*)res, N);
}

// Round 3
// 514.720 us; speedup vs baseline: 1.4062x; 1.1276x over previous
//
#include <hip/hip_runtime.h>

#define F 128
#define GRAPHS 64
#define GN_EPS 1e-5f
#define SCAN_B 256

// ---------------- degree + per-node edge count ----------------
__global__ void deg_kernel(const int* __restrict__ ei, const float* __restrict__ w,
                           float* __restrict__ deg, int* __restrict__ cnt, int E) {
    int e = blockIdx.x * blockDim.x + threadIdx.x;
    if (e >= E) return;
    int dst = ei[E + e];
    atomicAdd(&deg[dst], w[e]);
    atomicAdd(&cnt[dst], 1);
}

// ---------------- dinv + graph segment boundaries (batch is SORTED -> no atomics) --------
__global__ void dinv_start_kernel(const float* __restrict__ deg, float* __restrict__ dinv,
                                  const int* __restrict__ batch, int* __restrict__ gstart, int n) {
    int i = blockIdx.x * blockDim.x + threadIdx.x;
    if (i >= n) return;
    float d = deg[i];
    dinv[i] = (d > 0.f) ? rsqrtf(fmaxf(d, 1e-30f)) : 0.f;
    int b = batch[i];
    if (i == 0) {
        for (int g = 0; g <= b; ++g) gstart[g] = 0;
    } else {
        int bp = batch[i - 1];
        for (int g = bp + 1; g <= b; ++g) gstart[g] = i;
    }
    if (i == n - 1) {
        for (int g = b + 1; g <= GRAPHS; ++g) gstart[g] = n;
    }
}

// ---------------- exclusive scan of cnt -> offsets (3 phases) ----------------
__global__ void scan1_kernel(const int* __restrict__ cnt, int* __restrict__ excl,
                             int* __restrict__ blockSums, int n) {
    __shared__ int s[SCAN_B];
    int i = blockIdx.x * SCAN_B + threadIdx.x;
    int v = (i < n) ? cnt[i] : 0;
    s[threadIdx.x] = v;
    __syncthreads();
    for (int off = 1; off < SCAN_B; off <<= 1) {
        int t = (threadIdx.x >= off) ? s[threadIdx.x - off] : 0;
        __syncthreads();
        s[threadIdx.x] += t;
        __syncthreads();
    }
    if (i < n) excl[i] = s[threadIdx.x] - v;      // exclusive within block
    if (threadIdx.x == SCAN_B - 1) blockSums[blockIdx.x] = s[SCAN_B - 1];
}

__global__ void scan2_kernel(int* __restrict__ blockSums, int nb) {
    __shared__ int s[1024];
    int v = (threadIdx.x < nb) ? blockSums[threadIdx.x] : 0;
    s[threadIdx.x] = v;
    __syncthreads();
    for (int off = 1; off < 1024; off <<= 1) {
        int t = (threadIdx.x >= off) ? s[threadIdx.x - off] : 0;
        __syncthreads();
        s[threadIdx.x] += t;
        __syncthreads();
    }
    if (threadIdx.x < nb) blockSums[threadIdx.x] = s[threadIdx.x] - v;  // exclusive
}

__global__ void scan3_kernel(int* __restrict__ offs, const int* __restrict__ blockSums,
                             int* __restrict__ cur, int n, int total) {
    int i = blockIdx.x * SCAN_B + threadIdx.x;
    if (i < n) {
        int o = offs[i] + blockSums[blockIdx.x];
        offs[i] = o;
        cur[i] = o;
    }
    if (i == 0) offs[n] = total;
}

// ---------------- scatter edges into CSR (by dst), fuse norm computation ----------------
__global__ void scatter_kernel(const int* __restrict__ ei, const float* __restrict__ w,
                               const float* __restrict__ dinv, int* __restrict__ cur,
                               int* __restrict__ csr_src, float* __restrict__ csr_norm, int E) {
    int e = blockIdx.x * blockDim.x + threadIdx.x;
    if (e >= E) return;
    int s = ei[e];
    int d = ei[E + e];
    int p = atomicAdd(&cur[d], 1);
    csr_src[p] = s;
    csr_norm[p] = dinv[s] * w[e] * dinv[d];
}

// ---------------- one hop: hout[n] = sum_e norm[e] * hin[src[e]]  (gather form) ----------------
__global__ __launch_bounds__(256) void hop_kernel(const float4* __restrict__ hin,
                                                  float4* __restrict__ hout,
                                                  const int* __restrict__ offs,
                                                  const int* __restrict__ csr_src,
                                                  const float* __restrict__ csr_norm, int n) {
    int lane = threadIdx.x & 31;                       // 32 lanes * float4 = 128 feats
    int node = blockIdx.x * (blockDim.x >> 5) + (threadIdx.x >> 5);
    if (node >= n) return;
    int e0 = offs[node], e1 = offs[node + 1];
    float4 acc = make_float4(0.f, 0.f, 0.f, 0.f);
    for (int e = e0; e < e1; ++e) {
        int s = csr_src[e];
        float wv = csr_norm[e];
        float4 hv = hin[s * 32 + lane];
        acc.x += wv * hv.x; acc.y += wv * hv.y;
        acc.z += wv * hv.z; acc.w += wv * hv.w;
    }
    hout[node * 32 + lane] = acc;
}

// ---------------- out[M,128] (+)= A[M,128] @ W[128,128] (+bias) : fp32 VALU ----------------
#define MM_BM 64
__global__ __launch_bounds__(256) void matmul_kernel(const float* __restrict__ A,
                                                     const float* __restrict__ W,
                                                     float* __restrict__ out,
                                                     const float* __restrict__ bias,
                                                     int M, int addTo, int addBias) {
    __shared__ float Bs[32][128];        // 16 KB
    __shared__ float At[32][MM_BM + 4];  // transposed A tile, padded stride 68 (16B aligned)
    int tid = threadIdx.x;
    int tx = tid & 31;    // col group: cols tx*4..tx*4+3
    int ty = tid >> 5;    // row group: rows ty*8..ty*8+7
    int row0 = blockIdx.x * MM_BM;
    float acc[8][4] = {};

    for (int k0 = 0; k0 < 128; k0 += 32) {
        // stage B tile 32x128
        #pragma unroll
        for (int it = 0; it < 4; ++it) {
            int idx = tid + it * 256;      // float4 index 0..1023
            int kk = idx >> 5;
            int cc = (idx & 31) << 2;
            *(float4*)&Bs[kk][cc] = *(const float4*)&W[(size_t)(k0 + kk) * 128 + cc];
        }
        // stage A tile transposed: 64 rows x 32 k
        #pragma unroll
        for (int it = 0; it < 2; ++it) {
            int idx = tid + it * 256;      // 0..511
            int r = idx >> 3;              // 0..63
            int kq = (idx & 7) << 2;       // 0,4,...,28
            int nrow = row0 + r;
            float4 a = (nrow < M) ? *(const float4*)&A[(size_t)nrow * 128 + k0 + kq]
                                  : make_float4(0.f, 0.f, 0.f, 0.f);
            At[kq + 0][r] = a.x; At[kq + 1][r] = a.y;
            At[kq + 2][r] = a.z; At[kq + 3][r] = a.w;
        }
        __syncthreads();

        #pragma unroll 4
        for (int k = 0; k < 32; ++k) {
            float4 b = *(float4*)&Bs[k][tx << 2];
            float4 a0 = *(float4*)&At[k][ty * 8];
            float4 a1 = *(float4*)&At[k][ty * 8 + 4];
            float ar[8] = {a0.x, a0.y, a0.z, a0.w, a1.x, a1.y, a1.z, a1.w};
            #pragma unroll
            for (int r = 0; r < 8; ++r) {
                acc[r][0] += ar[r] * b.x;
                acc[r][1] += ar[r] * b.y;
                acc[r][2] += ar[r] * b.z;
                acc[r][3] += ar[r] * b.w;
            }
        }
        __syncthreads();
    }

    #pragma unroll
    for (int r = 0; r < 8; ++r) {
        int nrow = row0 + ty * 8 + r;
        if (nrow < M) {
            float* po = &out[(size_t)nrow * 128 + (tx << 2)];
            float4 o = make_float4(acc[r][0], acc[r][1], acc[r][2], acc[r][3]);
            if (addBias) {
                float4 bb = *(const float4*)&bias[tx << 2];
                o.x += bb.x; o.y += bb.y; o.z += bb.z; o.w += bb.w;
            }
            if (addTo) {
                float4 prev = *(float4*)po;
                o.x += prev.x; o.y += prev.y; o.z += prev.z; o.w += prev.w;
            }
            *(float4*)po = o;
        }
    }
}

// ---------------- per-graph sums S1, S2 ----------------
// 256 threads = 2 node-parities x 128 features; 32 nodes per block -> 1563 blocks.
// Each thread scans an ASCENDING node subsequence (stride 2), so the sorted-batch
// flush-on-graph-change accumulation stays valid.
#define STAT_NODES 32
__global__ __launch_bounds__(256) void stats_kernel(const float* __restrict__ out,
                                                    const int* __restrict__ batch,
                                                    float* __restrict__ S1, float* __restrict__ S2,
                                                    int n) {
    int f = threadIdx.x & 127;
    int par = threadIdx.x >> 7;              // 0 or 1
    int base = blockIdx.x * STAT_NODES;
    int n1 = min(base + STAT_NODES, n);
    int i0 = base + par;
    if (i0 >= n1) return;
    float s1 = 0.f, s2 = 0.f;
    int curg = batch[i0];
    for (int i = i0; i < n1; i += 2) {
        int g = batch[i];
        if (g != curg) {
            atomicAdd(&S1[curg * F + f], s1);
            atomicAdd(&S2[curg * F + f], s2);
            s1 = 0.f; s2 = 0.f; curg = g;
        }
        float v = out[(size_t)i * F + f];
        s1 += v; s2 += v * v;
    }
    atomicAdd(&S1[curg * F + f], s1);
    atomicAdd(&S2[curg * F + f], s2);
}

// ---------------- finalize mean/var -> sm = s*mean, Ag = gnw * rsqrt(var+eps) ----------------
__global__ void finalize_kernel(const float* __restrict__ S1, const float* __restrict__ S2,
                                const int* __restrict__ gstart, const float* __restrict__ gnw,
                                const float* __restrict__ gms,
                                float* __restrict__ sm, float* __restrict__ Ag, int GF) {
    int i = blockIdx.x * blockDim.x + threadIdx.x;
    if (i >= GF) return;
    int f = i & (F - 1);
    int g = i >> 7;
    float c = fmaxf((float)(gstart[g + 1] - gstart[g]), 1.f);
    float mean = S1[i] / c;
    float e2 = S2[i] / c;
    float s = gms[f];
    float var = e2 - 2.f * s * mean * mean + s * s * mean * mean;
    sm[i] = s * mean;
    Ag[i] = gnw[f] * rsqrtf(var + GN_EPS);
}

// ---------------- fused normalize + relu + residual ----------------
__global__ void final_kernel(const float4* __restrict__ y, const float4* __restrict__ out,
                             const int* __restrict__ batch, const float4* __restrict__ sm,
                             const float4* __restrict__ Ag, const float4* __restrict__ gnb,
                             float4* __restrict__ res, int n) {
    int idx = blockIdx.x * blockDim.x + threadIdx.x;  // over n*32 float4s
    if (idx >= n * 32) return;
    int node = idx >> 5;
    int q = idx & 31;
    int g = batch[node];
    float4 o = out[idx];
    float4 yv = y[idx];
    float4 m = sm[g * 32 + q];
    float4 a = Ag[g * 32 + q];
    float4 b = gnb[q];
    float4 r;
    r.x = yv.x + fmaxf(0.f, (o.x - m.x) * a.x + b.x);
    r.y = yv.y + fmaxf(0.f, (o.y - m.y) * a.y + b.y);
    r.z = yv.z + fmaxf(0.f, (o.z - m.z) * a.z + b.z);
    r.w = yv.w + fmaxf(0.f, (o.w - m.w) * a.w + b.w);
    res[idx] = r;
}

extern "C" void kernel_launch(void* const* d_in, const int* in_sizes, int n_in,
                              void* d_out, int out_size, void* d_ws, size_t ws_size,
                              hipStream_t stream) {
    const float* y     = (const float*)d_in[0];
    const int*   ei    = (const int*)d_in[1];
    const float* ew    = (const float*)d_in[2];
    const int*   batch = (const int*)d_in[3];
    const float* tag_w = (const float*)d_in[4];
    const float* tag_b = (const float*)d_in[5];
    const float* gnw   = (const float*)d_in[6];
    const float* gnb   = (const float*)d_in[7];
    const float* gms   = (const float*)d_in[8];
    float* res = (float*)d_out;

    const int N = in_sizes[0] / F;
    const int E = in_sizes[1] / 2;

    // ---- workspace layout (zero-init region first, one memset) ----
    char* p = (char*)d_ws;
    float* deg = (float*)p;      p += (size_t)N * 4;
    int*   cnt = (int*)p;        p += (size_t)N * 4;
    float* S1 = (float*)p;       p += (size_t)GRAPHS * F * 4;
    float* S2 = (float*)p;       p += (size_t)GRAPHS * F * 4;
    size_t zeroBytes = (size_t)(p - (char*)d_ws);
    int*   gstart = (int*)p;     p += 512;               // GRAPHS+1 ints (no zeroing needed)
    float* dinv = (float*)p;     p += (size_t)N * 4;
    int*   offs = (int*)p;       p += (size_t)(N + 4) * 4;
    int*   cur = (int*)p;        p += (size_t)N * 4;
    int*   blockSums = (int*)p;  p += 4096;
    int*   csr_src = (int*)p;    p += (size_t)E * 4;
    float* csr_norm = (float*)p; p += (size_t)E * 4;
    float* sm = (float*)p;       p += (size_t)GRAPHS * F * 4;
    float* Ag = (float*)p;       p += (size_t)GRAPHS * F * 4;
    float* h1 = (float*)p;       p += (size_t)N * F * 4;
    float* h2 = (float*)p;       p += (size_t)N * F * 4;
    float* outb = (float*)p;     p += (size_t)N * F * 4;

    hipMemsetAsync(d_ws, 0, zeroBytes, stream);

    int eb = (E + 255) / 256;
    int nb = (N + 255) / 256;
    int sb = (N + SCAN_B - 1) / SCAN_B;

    deg_kernel<<<eb, 256, 0, stream>>>(ei, ew, deg, cnt, E);
    dinv_start_kernel<<<nb, 256, 0, stream>>>(deg, dinv, batch, gstart, N);
    scan1_kernel<<<sb, SCAN_B, 0, stream>>>(cnt, offs, blockSums, N);
    scan2_kernel<<<1, 1024, 0, stream>>>(blockSums, sb);
    scan3_kernel<<<sb, SCAN_B, 0, stream>>>(offs, blockSums, cur, N, E);
    scatter_kernel<<<eb, 256, 0, stream>>>(ei, ew, dinv, cur, csr_src, csr_norm, E);

    int mb = (N + MM_BM - 1) / MM_BM;
    int hb = (N + 7) / 8;
    matmul_kernel<<<mb, 256, 0, stream>>>(y, tag_w + 0 * F * F, outb, tag_b, N, 0, 0);
    hop_kernel<<<hb, 256, 0, stream>>>((const float4*)y, (float4*)h1, offs, csr_src, csr_norm, N);
    matmul_kernel<<<mb, 256, 0, stream>>>(h1, tag_w + 1 * F * F, outb, tag_b, N, 1, 0);
    hop_kernel<<<hb, 256, 0, stream>>>((const float4*)h1, (float4*)h2, offs, csr_src, csr_norm, N);
    matmul_kernel<<<mb, 256, 0, stream>>>(h2, tag_w + 2 * F * F, outb, tag_b, N, 1, 0);
    hop_kernel<<<hb, 256, 0, stream>>>((const float4*)h2, (float4*)h1, offs, csr_src, csr_norm, N);
    matmul_kernel<<<mb, 256, 0, stream>>>(h1, tag_w + 3 * F * F, outb, tag_b, N, 1, 1);

    stats_kernel<<<(N + STAT_NODES - 1) / STAT_NODES, 256, 0, stream>>>(outb, batch, S1, S2, N);
    finalize_kernel<<<(GRAPHS * F + 255) / 256, 256, 0, stream>>>(S1, S2, gstart, gnw, gms, sm, Ag, GRAPHS * F);
    final_kernel<<<(N * 32 + 255) / 256, 256, 0, stream>>>((const float4*)y, (const float4*)outb,
                                                           batch, (const float4*)sm, (const float4*)Ag,
                                                           (const float4*)gnb, (float4*)res, N);
}

// Round 4
// 465.801 us; speedup vs baseline: 1.5539x; 1.1050x over previous
//
#include <hip/hip_runtime.h>

#define F 128
#define GRAPHS 64
#define GN_EPS 1e-5f
#define SCAN_B 256

__device__ __forceinline__ unsigned short f2b(float f) {      // fp32 -> bf16 RNE
    unsigned u = __float_as_uint(f);
    unsigned r = (u + 0x7fffu + ((u >> 16) & 1u)) >> 16;
    return (unsigned short)r;
}
__device__ __forceinline__ float b2f(unsigned short h) {      // bf16 -> fp32
    return __uint_as_float(((unsigned)h) << 16);
}

// ---------------- degree + count in ONE packed 64-bit atomic per edge ----------------
// bits [0,40): sum of w quantized at 2^24 (max deg ~64 -> < 2^30, no overflow)
// bits [40,64): edge count
__global__ void deg_kernel(const int* __restrict__ ei, const float* __restrict__ w,
                           unsigned long long* __restrict__ packed, int E) {
    int e = blockIdx.x * blockDim.x + threadIdx.x;
    if (e >= E) return;
    int dst = ei[E + e];
    unsigned q = (unsigned)(w[e] * 16777216.0f + 0.5f);
    atomicAdd(&packed[dst], (1ull << 40) | (unsigned long long)q);
}

// ---------------- decode packed -> dinv + cnt; graph starts (batch sorted, no atomics) ----
__global__ void dinv_start_kernel(const unsigned long long* __restrict__ packed,
                                  float* __restrict__ dinv, int* __restrict__ cnt,
                                  const int* __restrict__ batch, int* __restrict__ gstart, int n) {
    int i = blockIdx.x * blockDim.x + threadIdx.x;
    if (i >= n) return;
    unsigned long long p = packed[i];
    cnt[i] = (int)(p >> 40);
    float d = (float)(p & 0xFFFFFFFFFFull) * 5.9604644775390625e-8f;  // / 2^24
    dinv[i] = (d > 0.f) ? rsqrtf(fmaxf(d, 1e-30f)) : 0.f;
    int b = batch[i];
    if (i == 0) {
        for (int g = 0; g <= b; ++g) gstart[g] = 0;
    } else {
        int bp = batch[i - 1];
        for (int g = bp + 1; g <= b; ++g) gstart[g] = i;
    }
    if (i == n - 1) {
        for (int g = b + 1; g <= GRAPHS; ++g) gstart[g] = n;
    }
}

// ---------------- exclusive scan of cnt -> offsets (3 phases) ----------------
__global__ void scan1_kernel(const int* __restrict__ cnt, int* __restrict__ excl,
                             int* __restrict__ blockSums, int n) {
    __shared__ int s[SCAN_B];
    int i = blockIdx.x * SCAN_B + threadIdx.x;
    int v = (i < n) ? cnt[i] : 0;
    s[threadIdx.x] = v;
    __syncthreads();
    for (int off = 1; off < SCAN_B; off <<= 1) {
        int t = (threadIdx.x >= off) ? s[threadIdx.x - off] : 0;
        __syncthreads();
        s[threadIdx.x] += t;
        __syncthreads();
    }
    if (i < n) excl[i] = s[threadIdx.x] - v;
    if (threadIdx.x == SCAN_B - 1) blockSums[blockIdx.x] = s[SCAN_B - 1];
}

__global__ void scan2_kernel(int* __restrict__ blockSums, int nb) {
    __shared__ int s[1024];
    int v = (threadIdx.x < nb) ? blockSums[threadIdx.x] : 0;
    s[threadIdx.x] = v;
    __syncthreads();
    for (int off = 1; off < 1024; off <<= 1) {
        int t = (threadIdx.x >= off) ? s[threadIdx.x - off] : 0;
        __syncthreads();
        s[threadIdx.x] += t;
        __syncthreads();
    }
    if (threadIdx.x < nb) blockSums[threadIdx.x] = s[threadIdx.x] - v;
}

__global__ void scan3_kernel(int* __restrict__ offs, const int* __restrict__ blockSums,
                             int* __restrict__ cur, int n, int total) {
    int i = blockIdx.x * SCAN_B + threadIdx.x;
    if (i < n) {
        int o = offs[i] + blockSums[blockIdx.x];
        offs[i] = o;
        cur[i] = o;
    }
    if (i == 0) offs[n] = total;
}

// ---------------- scatter edges into CSR: single 8B write (src, dinv[src]*w) ----------------
__global__ void scatter_kernel(const int* __restrict__ ei, const float* __restrict__ w,
                               const float* __restrict__ dinv, int* __restrict__ cur,
                               uint2* __restrict__ csr, int E) {
    int e = blockIdx.x * blockDim.x + threadIdx.x;
    if (e >= E) return;
    int s = ei[e];
    int d = ei[E + e];
    int p = atomicAdd(&cur[d], 1);
    float v = dinv[s] * w[e];
    csr[p] = make_uint2((unsigned)s, __float_as_uint(v));
}

// ---------------- fp32 -> bf16 row conversion (for y feeding hop 1) ----------------
__global__ void f2b_kernel(const float4* __restrict__ in, ushort4* __restrict__ out, int n4) {
    int i = blockIdx.x * blockDim.x + threadIdx.x;
    if (i >= n4) return;
    float4 v = in[i];
    out[i] = make_ushort4(f2b(v.x), f2b(v.y), f2b(v.z), f2b(v.w));
}

// ---------------- one hop (bf16 rows): hout[d] = dinv[d] * sum_e (dinv[s]*w) * hin[s] ------
__global__ __launch_bounds__(256) void hop_kernel(const ushort4* __restrict__ hin,
                                                  ushort4* __restrict__ hout,
                                                  const int* __restrict__ offs,
                                                  const uint2* __restrict__ csr,
                                                  const float* __restrict__ dinv, int n) {
    int lane = threadIdx.x & 31;                       // 32 lanes * 4 bf16 = 128 feats
    int node = blockIdx.x * 8 + (threadIdx.x >> 5);
    if (node >= n) return;
    int e0 = offs[node], e1 = offs[node + 1];
    float ax = 0.f, ay = 0.f, az = 0.f, aw = 0.f;
    for (int e = e0; e < e1; ++e) {
        uint2 ed = csr[e];
        float wv = __uint_as_float(ed.y);
        ushort4 hv = hin[(size_t)ed.x * 32 + lane];
        ax += wv * b2f(hv.x); ay += wv * b2f(hv.y);
        az += wv * b2f(hv.z); aw += wv * b2f(hv.w);
    }
    float dd = dinv[node];
    hout[(size_t)node * 32 + lane] =
        make_ushort4(f2b(ax * dd), f2b(ay * dd), f2b(az * dd), f2b(aw * dd));
}

// ---------------- out[M,128] (+)= A[M,128] @ W[128,128] (+bias) : fp32 VALU ----------------
// A may be fp32 (first term, reads y) or bf16 (hop outputs).
#define MM_BM 64
template <bool ABF>
__global__ __launch_bounds__(256) void matmul_kernel(const void* __restrict__ Av,
                                                     const float* __restrict__ W,
                                                     float* __restrict__ out,
                                                     const float* __restrict__ bias,
                                                     int M, int addTo, int addBias) {
    __shared__ float Bs[32][128];        // 16 KB
    __shared__ float At[32][MM_BM + 4];  // transposed A tile, padded
    int tid = threadIdx.x;
    int tx = tid & 31;
    int ty = tid >> 5;
    int row0 = blockIdx.x * MM_BM;
    float acc[8][4] = {};

    for (int k0 = 0; k0 < 128; k0 += 32) {
        #pragma unroll
        for (int it = 0; it < 4; ++it) {
            int idx = tid + it * 256;
            int kk = idx >> 5;
            int cc = (idx & 31) << 2;
            *(float4*)&Bs[kk][cc] = *(const float4*)&W[(size_t)(k0 + kk) * 128 + cc];
        }
        #pragma unroll
        for (int it = 0; it < 2; ++it) {
            int idx = tid + it * 256;
            int r = idx >> 3;
            int kq = (idx & 7) << 2;
            int nrow = row0 + r;
            float x0, x1, x2, x3;
            if (nrow < M) {
                if (ABF) {
                    ushort4 a = ((const ushort4*)Av)[(size_t)nrow * 32 + ((k0 + kq) >> 2)];
                    x0 = b2f(a.x); x1 = b2f(a.y); x2 = b2f(a.z); x3 = b2f(a.w);
                } else {
                    float4 a = *(const float4*)&((const float*)Av)[(size_t)nrow * 128 + k0 + kq];
                    x0 = a.x; x1 = a.y; x2 = a.z; x3 = a.w;
                }
            } else { x0 = x1 = x2 = x3 = 0.f; }
            At[kq + 0][r] = x0; At[kq + 1][r] = x1;
            At[kq + 2][r] = x2; At[kq + 3][r] = x3;
        }
        __syncthreads();

        #pragma unroll 4
        for (int k = 0; k < 32; ++k) {
            float4 b = *(float4*)&Bs[k][tx << 2];
            float4 a0 = *(float4*)&At[k][ty * 8];
            float4 a1 = *(float4*)&At[k][ty * 8 + 4];
            float ar[8] = {a0.x, a0.y, a0.z, a0.w, a1.x, a1.y, a1.z, a1.w};
            #pragma unroll
            for (int r = 0; r < 8; ++r) {
                acc[r][0] += ar[r] * b.x;
                acc[r][1] += ar[r] * b.y;
                acc[r][2] += ar[r] * b.z;
                acc[r][3] += ar[r] * b.w;
            }
        }
        __syncthreads();
    }

    #pragma unroll
    for (int r = 0; r < 8; ++r) {
        int nrow = row0 + ty * 8 + r;
        if (nrow < M) {
            float* po = &out[(size_t)nrow * 128 + (tx << 2)];
            float4 o = make_float4(acc[r][0], acc[r][1], acc[r][2], acc[r][3]);
            if (addBias) {
                float4 bb = *(const float4*)&bias[tx << 2];
                o.x += bb.x; o.y += bb.y; o.z += bb.z; o.w += bb.w;
            }
            if (addTo) {
                float4 prev = *(float4*)po;
                o.x += prev.x; o.y += prev.y; o.z += prev.z; o.w += prev.w;
            }
            *(float4*)po = o;
        }
    }
}

// ---------------- per-graph sums S1, S2 (parallel; sorted-batch flush trick) ----------------
#define STAT_NODES 32
__global__ __launch_bounds__(256) void stats_kernel(const float* __restrict__ out,
                                                    const int* __restrict__ batch,
                                                    float* __restrict__ S1, float* __restrict__ S2,
                                                    int n) {
    int f = threadIdx.x & 127;
    int par = threadIdx.x >> 7;
    int base = blockIdx.x * STAT_NODES;
    int n1 = min(base + STAT_NODES, n);
    int i0 = base + par;
    if (i0 >= n1) return;
    float s1 = 0.f, s2 = 0.f;
    int curg = batch[i0];
    for (int i = i0; i < n1; i += 2) {
        int g = batch[i];
        if (g != curg) {
            atomicAdd(&S1[curg * F + f], s1);
            atomicAdd(&S2[curg * F + f], s2);
            s1 = 0.f; s2 = 0.f; curg = g;
        }
        float v = out[(size_t)i * F + f];
        s1 += v; s2 += v * v;
    }
    atomicAdd(&S1[curg * F + f], s1);
    atomicAdd(&S2[curg * F + f], s2);
}

// ---------------- finalize mean/var -> sm = s*mean, Ag = gnw * rsqrt(var+eps) ----------------
__global__ void finalize_kernel(const float* __restrict__ S1, const float* __restrict__ S2,
                                const int* __restrict__ gstart, const float* __restrict__ gnw,
                                const float* __restrict__ gms,
                                float* __restrict__ sm, float* __restrict__ Ag, int GF) {
    int i = blockIdx.x * blockDim.x + threadIdx.x;
    if (i >= GF) return;
    int f = i & (F - 1);
    int g = i >> 7;
    float c = fmaxf((float)(gstart[g + 1] - gstart[g]), 1.f);
    float mean = S1[i] / c;
    float e2 = S2[i] / c;
    float s = gms[f];
    float var = e2 - 2.f * s * mean * mean + s * s * mean * mean;
    sm[i] = s * mean;
    Ag[i] = gnw[f] * rsqrtf(var + GN_EPS);
}

// ---------------- fused normalize + relu + residual ----------------
__global__ void final_kernel(const float4* __restrict__ y, const float4* __restrict__ out,
                             const int* __restrict__ batch, const float4* __restrict__ sm,
                             const float4* __restrict__ Ag, const float4* __restrict__ gnb,
                             float4* __restrict__ res, int n) {
    int idx = blockIdx.x * blockDim.x + threadIdx.x;
    if (idx >= n * 32) return;
    int node = idx >> 5;
    int q = idx & 31;
    int g = batch[node];
    float4 o = out[idx];
    float4 yv = y[idx];
    float4 m = sm[g * 32 + q];
    float4 a = Ag[g * 32 + q];
    float4 b = gnb[q];
    float4 r;
    r.x = yv.x + fmaxf(0.f, (o.x - m.x) * a.x + b.x);
    r.y = yv.y + fmaxf(0.f, (o.y - m.y) * a.y + b.y);
    r.z = yv.z + fmaxf(0.f, (o.z - m.z) * a.z + b.z);
    r.w = yv.w + fmaxf(0.f, (o.w - m.w) * a.w + b.w);
    res[idx] = r;
}

extern "C" void kernel_launch(void* const* d_in, const int* in_sizes, int n_in,
                              void* d_out, int out_size, void* d_ws, size_t ws_size,
                              hipStream_t stream) {
    const float* y     = (const float*)d_in[0];
    const int*   ei    = (const int*)d_in[1];
    const float* ew    = (const float*)d_in[2];
    const int*   batch = (const int*)d_in[3];
    const float* tag_w = (const float*)d_in[4];
    const float* tag_b = (const float*)d_in[5];
    const float* gnw   = (const float*)d_in[6];
    const float* gnb   = (const float*)d_in[7];
    const float* gms   = (const float*)d_in[8];
    float* res = (float*)d_out;

    const int N = in_sizes[0] / F;
    const int E = in_sizes[1] / 2;

    // ---- workspace layout (zero-init region first, one memset) ----
    char* p = (char*)d_ws;
    unsigned long long* packed = (unsigned long long*)p; p += (size_t)N * 8;
    float* S1 = (float*)p;       p += (size_t)GRAPHS * F * 4;
    float* S2 = (float*)p;       p += (size_t)GRAPHS * F * 4;
    size_t zeroBytes = (size_t)(p - (char*)d_ws);
    int*   gstart = (int*)p;     p += 512;
    float* dinv = (float*)p;     p += (size_t)N * 4;
    int*   cnt = (int*)p;        p += (size_t)N * 4;
    int*   offs = (int*)p;       p += (size_t)(N + 4) * 4;
    int*   cur = (int*)p;        p += (size_t)N * 4;
    int*   blockSums = (int*)p;  p += 4096;
    uint2* csr = (uint2*)p;      p += (size_t)E * 8;
    float* sm = (float*)p;       p += (size_t)GRAPHS * F * 4;
    float* Ag = (float*)p;       p += (size_t)GRAPHS * F * 4;
    ushort4* y_bf = (ushort4*)p; p += (size_t)N * F * 2;
    ushort4* h1 = (ushort4*)p;   p += (size_t)N * F * 2;
    ushort4* h2 = (ushort4*)p;   p += (size_t)N * F * 2;
    float* outb = (float*)p;     p += (size_t)N * F * 4;

    hipMemsetAsync(d_ws, 0, zeroBytes, stream);

    int eb = (E + 255) / 256;
    int nb = (N + 255) / 256;
    int sb = (N + SCAN_B - 1) / SCAN_B;

    deg_kernel<<<eb, 256, 0, stream>>>(ei, ew, packed, E);
    dinv_start_kernel<<<nb, 256, 0, stream>>>(packed, dinv, cnt, batch, gstart, N);
    scan1_kernel<<<sb, SCAN_B, 0, stream>>>(cnt, offs, blockSums, N);
    scan2_kernel<<<1, 1024, 0, stream>>>(blockSums, sb);
    scan3_kernel<<<sb, SCAN_B, 0, stream>>>(offs, blockSums, cur, N, E);
    f2b_kernel<<<(N * 32 + 255) / 256, 256, 0, stream>>>((const float4*)y, y_bf, N * 32);
    scatter_kernel<<<eb, 256, 0, stream>>>(ei, ew, dinv, cur, csr, E);

    int mb = (N + MM_BM - 1) / MM_BM;
    int hb = (N + 7) / 8;
    matmul_kernel<false><<<mb, 256, 0, stream>>>(y, tag_w + 0 * F * F, outb, tag_b, N, 0, 0);
    hop_kernel<<<hb, 256, 0, stream>>>(y_bf, h1, offs, csr, dinv, N);
    matmul_kernel<true><<<mb, 256, 0, stream>>>(h1, tag_w + 1 * F * F, outb, tag_b, N, 1, 0);
    hop_kernel<<<hb, 256, 0, stream>>>(h1, h2, offs, csr, dinv, N);
    matmul_kernel<true><<<mb, 256, 0, stream>>>(h2, tag_w + 2 * F * F, outb, tag_b, N, 1, 0);
    hop_kernel<<<hb, 256, 0, stream>>>(h2, h1, offs, csr, dinv, N);
    matmul_kernel<true><<<mb, 256, 0, stream>>>(h1, tag_w + 3 * F * F, outb, tag_b, N, 1, 1);

    stats_kernel<<<(N + STAT_NODES - 1) / STAT_NODES, 256, 0, stream>>>(outb, batch, S1, S2, N);
    finalize_kernel<<<(GRAPHS * F + 255) / 256, 256, 0, stream>>>(S1, S2, gstart, gnw, gms, sm, Ag, GRAPHS * F);
    final_kernel<<<(N * 32 + 255) / 256, 256, 0, stream>>>((const float4*)y, (const float4*)outb,
                                                           batch, (const float4*)sm, (const float4*)Ag,
                                                           (const float4*)gnb, (float4*)res, N);
}

// Round 5
// 357.556 us; speedup vs baseline: 2.0243x; 1.3027x over previous
//
#include <hip/hip_runtime.h>

#define F 128
#define GRAPHS 64
#define GN_EPS 1e-5f
#define SCAN_B 256

typedef short short8 __attribute__((ext_vector_type(8)));
typedef float f32x4 __attribute__((ext_vector_type(4)));

__device__ __forceinline__ unsigned short f2b(float f) {      // fp32 -> bf16 RNE
    unsigned u = __float_as_uint(f);
    unsigned r = (u + 0x7fffu + ((u >> 16) & 1u)) >> 16;
    return (unsigned short)r;
}
__device__ __forceinline__ float b2f(unsigned short h) {      // bf16 -> fp32
    return __uint_as_float(((unsigned)h) << 16);
}

// ---------------- degree + count in ONE packed 64-bit atomic per edge --------------
// bits [0,40): sum of w quantized at 2^24; bits [40,64): edge count.
// The RETURN value's count field is this edge's rank within its dst segment.
__global__ void deg_kernel(const int* __restrict__ ei, const float* __restrict__ w,
                           unsigned long long* __restrict__ packed,
                           unsigned short* __restrict__ rank, int E) {
    int e = blockIdx.x * blockDim.x + threadIdx.x;
    if (e >= E) return;
    int dst = ei[E + e];
    unsigned q = (unsigned)(w[e] * 16777216.0f + 0.5f);
    unsigned long long old = atomicAdd(&packed[dst], (1ull << 40) | (unsigned long long)q);
    rank[e] = (unsigned short)(old >> 40);
}

// ---------------- decode packed -> dinv + cnt; graph starts (batch sorted) --------
__global__ void dinv_start_kernel(const unsigned long long* __restrict__ packed,
                                  float* __restrict__ dinv, int* __restrict__ cnt,
                                  const int* __restrict__ batch, int* __restrict__ gstart, int n) {
    int i = blockIdx.x * blockDim.x + threadIdx.x;
    if (i >= n) return;
    unsigned long long p = packed[i];
    cnt[i] = (int)(p >> 40);
    float d = (float)(p & 0xFFFFFFFFFFull) * 5.9604644775390625e-8f;  // / 2^24
    dinv[i] = (d > 0.f) ? rsqrtf(fmaxf(d, 1e-30f)) : 0.f;
    int b = batch[i];
    if (i == 0) {
        for (int g = 0; g <= b; ++g) gstart[g] = 0;
    } else {
        int bp = batch[i - 1];
        for (int g = bp + 1; g <= b; ++g) gstart[g] = i;
    }
    if (i == n - 1) {
        for (int g = b + 1; g <= GRAPHS; ++g) gstart[g] = n;
    }
}

// ---------------- exclusive scan of cnt -> offsets (3 phases) ----------------
__global__ void scan1_kernel(const int* __restrict__ cnt, int* __restrict__ excl,
                             int* __restrict__ blockSums, int n) {
    __shared__ int s[SCAN_B];
    int i = blockIdx.x * SCAN_B + threadIdx.x;
    int v = (i < n) ? cnt[i] : 0;
    s[threadIdx.x] = v;
    __syncthreads();
    for (int off = 1; off < SCAN_B; off <<= 1) {
        int t = (threadIdx.x >= off) ? s[threadIdx.x - off] : 0;
        __syncthreads();
        s[threadIdx.x] += t;
        __syncthreads();
    }
    if (i < n) excl[i] = s[threadIdx.x] - v;
    if (threadIdx.x == SCAN_B - 1) blockSums[blockIdx.x] = s[SCAN_B - 1];
}

__global__ void scan2_kernel(int* __restrict__ blockSums, int nb) {
    __shared__ int s[1024];
    int v = (threadIdx.x < nb) ? blockSums[threadIdx.x] : 0;
    s[threadIdx.x] = v;
    __syncthreads();
    for (int off = 1; off < 1024; off <<= 1) {
        int t = (threadIdx.x >= off) ? s[threadIdx.x - off] : 0;
        __syncthreads();
        s[threadIdx.x] += t;
        __syncthreads();
    }
    if (threadIdx.x < nb) blockSums[threadIdx.x] = s[threadIdx.x] - v;
}

__global__ void scan3_kernel(int* __restrict__ offs, const int* __restrict__ blockSums,
                             int n, int total) {
    int i = blockIdx.x * SCAN_B + threadIdx.x;
    if (i < n) offs[i] += blockSums[blockIdx.x];
    if (i == 0) offs[n] = total;
}

// ---------------- scatter edges into CSR: NO atomics, single 4B write per edge ------
// entry = (src:16 | bf16(dinv[src]*w):16)
__global__ void scatter_kernel(const int* __restrict__ ei, const float* __restrict__ w,
                               const float* __restrict__ dinv, const int* __restrict__ offs,
                               const unsigned short* __restrict__ rank,
                               unsigned* __restrict__ csr, int E) {
    int e = blockIdx.x * blockDim.x + threadIdx.x;
    if (e >= E) return;
    int s = ei[e];
    int d = ei[E + e];
    unsigned v = ((unsigned)s << 16) | (unsigned)f2b(dinv[s] * w[e]);
    csr[offs[d] + (int)rank[e]] = v;
}

// ---------------- fp32 -> bf16 row conversion (y -> hcat slice 0) ----------------
__global__ void f2b_kernel(const float4* __restrict__ in, ushort4* __restrict__ out, int n4) {
    int i = blockIdx.x * blockDim.x + threadIdx.x;
    if (i >= n4) return;
    float4 v = in[i];
    out[i] = make_ushort4(f2b(v.x), f2b(v.y), f2b(v.z), f2b(v.w));
}

// ---------------- tag_w [4][k=128][n=128] fp32 -> WbfT [4][n=128][k=128] bf16 -------
__global__ void wcvt_kernel(const float* __restrict__ w, unsigned short* __restrict__ wt) {
    int i = blockIdx.x * blockDim.x + threadIdx.x;   // over 4*128*128
    int s = i >> 14;
    int n = (i >> 7) & 127;
    int k = i & 127;
    wt[i] = f2b(w[s * 16384 + k * 128 + n]);
}

// ---------------- one hop (bf16 rows): hout[d] = dinv[d] * sum_e w_e * hin[src_e] ----
__global__ __launch_bounds__(256) void hop_kernel(const ushort4* __restrict__ hin,
                                                  ushort4* __restrict__ hout,
                                                  const int* __restrict__ offs,
                                                  const unsigned* __restrict__ csr,
                                                  const float* __restrict__ dinv, int n) {
    int lane = threadIdx.x & 31;                       // 32 lanes * 4 bf16 = 128 feats
    int node = blockIdx.x * 8 + (threadIdx.x >> 5);
    if (node >= n) return;
    int e0 = offs[node], e1 = offs[node + 1];
    float ax = 0.f, ay = 0.f, az = 0.f, aw = 0.f;
    for (int e = e0; e < e1; ++e) {
        unsigned ed = csr[e];
        float wv = b2f((unsigned short)(ed & 0xffffu));
        ushort4 hv = hin[(size_t)(ed >> 16) * 32 + lane];
        ax += wv * b2f(hv.x); ay += wv * b2f(hv.y);
        az += wv * b2f(hv.z); aw += wv * b2f(hv.w);
    }
    float dd = dinv[node];
    hout[(size_t)node * 32 + lane] =
        make_ushort4(f2b(ax * dd), f2b(ay * dd), f2b(az * dd), f2b(aw * dd));
}

// ---------------- fused GEMM: outb[N,128] = [y|h1|h2|h3] @ [W0;W1;W2;W3] + bias ------
// bf16 MFMA 16x16x32. Block = 256 thr = 4 waves in 2x2 grid; M-tile 64, N full 128.
// A-frag: A[m=lane&15][k=quad*8+j]; B-frag: B[k=quad*8+j][n=lane&15] (from W^T rows);
// C/D: row=quad*4+r, col=lane&15  [m89/m120-verified maps].
// OOB rows read garbage but GEMM rows don't mix -> guarded store drops them.
__global__ __launch_bounds__(256) void gemm_kernel(const unsigned short* __restrict__ hcat,
                                                   const unsigned short* __restrict__ WbfT,
                                                   const float* __restrict__ bias,
                                                   float* __restrict__ outb,
                                                   int M, size_t NF) {
    int lane = threadIdx.x & 63;
    int wid = threadIdx.x >> 6;
    int wr = wid & 1, wc = wid >> 1;
    int quad = lane >> 4, l15 = lane & 15;
    int row0 = blockIdx.x * 64;
    f32x4 acc[2][4] = {};

    for (int s = 0; s < 4; ++s) {
        const unsigned short* As = hcat + (size_t)s * NF;
        const unsigned short* Bs = WbfT + s * 16384;
        const unsigned short* ar0 = As + (size_t)(row0 + wr * 32 + l15) * 128;
        const unsigned short* ar1 = ar0 + 16 * 128;
        const unsigned short* br = Bs + (wc * 64 + l15) * 128;
        #pragma unroll
        for (int k0 = 0; k0 < 128; k0 += 32) {
            int ko = k0 + quad * 8;
            short8 a0 = *(const short8*)(ar0 + ko);
            short8 a1 = *(const short8*)(ar1 + ko);
            short8 b0 = *(const short8*)(br + ko);
            short8 b1 = *(const short8*)(br + 16 * 128 + ko);
            short8 b2 = *(const short8*)(br + 32 * 128 + ko);
            short8 b3 = *(const short8*)(br + 48 * 128 + ko);
            acc[0][0] = __builtin_amdgcn_mfma_f32_16x16x32_bf16(a0, b0, acc[0][0], 0, 0, 0);
            acc[0][1] = __builtin_amdgcn_mfma_f32_16x16x32_bf16(a0, b1, acc[0][1], 0, 0, 0);
            acc[0][2] = __builtin_amdgcn_mfma_f32_16x16x32_bf16(a0, b2, acc[0][2], 0, 0, 0);
            acc[0][3] = __builtin_amdgcn_mfma_f32_16x16x32_bf16(a0, b3, acc[0][3], 0, 0, 0);
            acc[1][0] = __builtin_amdgcn_mfma_f32_16x16x32_bf16(a1, b0, acc[1][0], 0, 0, 0);
            acc[1][1] = __builtin_amdgcn_mfma_f32_16x16x32_bf16(a1, b1, acc[1][1], 0, 0, 0);
            acc[1][2] = __builtin_amdgcn_mfma_f32_16x16x32_bf16(a1, b2, acc[1][2], 0, 0, 0);
            acc[1][3] = __builtin_amdgcn_mfma_f32_16x16x32_bf16(a1, b3, acc[1][3], 0, 0, 0);
        }
    }

    #pragma unroll
    for (int mt = 0; mt < 2; ++mt) {
        #pragma unroll
        for (int r = 0; r < 4; ++r) {
            int row = row0 + wr * 32 + mt * 16 + quad * 4 + r;
            if (row < M) {
                #pragma unroll
                for (int nt = 0; nt < 4; ++nt) {
                    int col = wc * 64 + nt * 16 + l15;
                    outb[(size_t)row * 128 + col] = acc[mt][nt][r] + bias[col];
                }
            }
        }
    }
}

// ---------------- per-graph sums S1, S2 (parallel; sorted-batch flush trick) ----------
#define STAT_NODES 32
__global__ __launch_bounds__(256) void stats_kernel(const float* __restrict__ out,
                                                    const int* __restrict__ batch,
                                                    float* __restrict__ S1, float* __restrict__ S2,
                                                    int n) {
    int f = threadIdx.x & 127;
    int par = threadIdx.x >> 7;
    int base = blockIdx.x * STAT_NODES;
    int n1 = min(base + STAT_NODES, n);
    int i0 = base + par;
    if (i0 >= n1) return;
    float s1 = 0.f, s2 = 0.f;
    int curg = batch[i0];
    for (int i = i0; i < n1; i += 2) {
        int g = batch[i];
        if (g != curg) {
            atomicAdd(&S1[curg * F + f], s1);
            atomicAdd(&S2[curg * F + f], s2);
            s1 = 0.f; s2 = 0.f; curg = g;
        }
        float v = out[(size_t)i * F + f];
        s1 += v; s2 += v * v;
    }
    atomicAdd(&S1[curg * F + f], s1);
    atomicAdd(&S2[curg * F + f], s2);
}

// ---------------- finalize mean/var -> sm = s*mean, Ag = gnw * rsqrt(var+eps) --------
__global__ void finalize_kernel(const float* __restrict__ S1, const float* __restrict__ S2,
                                const int* __restrict__ gstart, const float* __restrict__ gnw,
                                const float* __restrict__ gms,
                                float* __restrict__ sm, float* __restrict__ Ag, int GF) {
    int i = blockIdx.x * blockDim.x + threadIdx.x;
    if (i >= GF) return;
    int f = i & (F - 1);
    int g = i >> 7;
    float c = fmaxf((float)(gstart[g + 1] - gstart[g]), 1.f);
    float mean = S1[i] / c;
    float e2 = S2[i] / c;
    float s = gms[f];
    float var = e2 - 2.f * s * mean * mean + s * s * mean * mean;
    sm[i] = s * mean;
    Ag[i] = gnw[f] * rsqrtf(var + GN_EPS);
}

// ---------------- fused normalize + relu + residual ----------------
__global__ void final_kernel(const float4* __restrict__ y, const float4* __restrict__ out,
                             const int* __restrict__ batch, const float4* __restrict__ sm,
                             const float4* __restrict__ Ag, const float4* __restrict__ gnb,
                             float4* __restrict__ res, int n) {
    int idx = blockIdx.x * blockDim.x + threadIdx.x;
    if (idx >= n * 32) return;
    int node = idx >> 5;
    int q = idx & 31;
    int g = batch[node];
    float4 o = out[idx];
    float4 yv = y[idx];
    float4 m = sm[g * 32 + q];
    float4 a = Ag[g * 32 + q];
    float4 b = gnb[q];
    float4 r;
    r.x = yv.x + fmaxf(0.f, (o.x - m.x) * a.x + b.x);
    r.y = yv.y + fmaxf(0.f, (o.y - m.y) * a.y + b.y);
    r.z = yv.z + fmaxf(0.f, (o.z - m.z) * a.z + b.z);
    r.w = yv.w + fmaxf(0.f, (o.w - m.w) * a.w + b.w);
    res[idx] = r;
}

extern "C" void kernel_launch(void* const* d_in, const int* in_sizes, int n_in,
                              void* d_out, int out_size, void* d_ws, size_t ws_size,
                              hipStream_t stream) {
    const float* y     = (const float*)d_in[0];
    const int*   ei    = (const int*)d_in[1];
    const float* ew    = (const float*)d_in[2];
    const int*   batch = (const int*)d_in[3];
    const float* tag_w = (const float*)d_in[4];
    const float* tag_b = (const float*)d_in[5];
    const float* gnw   = (const float*)d_in[6];
    const float* gnb   = (const float*)d_in[7];
    const float* gms   = (const float*)d_in[8];
    float* res = (float*)d_out;

    const int N = in_sizes[0] / F;
    const int E = in_sizes[1] / 2;
    const size_t NF = (size_t)N * F;

    // ---- workspace layout (zero-init region first, one memset) ----
    char* p = (char*)d_ws;
    unsigned long long* packed = (unsigned long long*)p; p += (size_t)N * 8;
    float* S1 = (float*)p;       p += (size_t)GRAPHS * F * 4;
    float* S2 = (float*)p;       p += (size_t)GRAPHS * F * 4;
    size_t zeroBytes = (size_t)(p - (char*)d_ws);
    int*   gstart = (int*)p;     p += 512;
    float* dinv = (float*)p;     p += (size_t)N * 4;
    int*   cnt = (int*)p;        p += (size_t)N * 4;
    int*   offs = (int*)p;       p += (size_t)(N + 4) * 4;
    int*   blockSums = (int*)p;  p += 4096;
    unsigned short* rank = (unsigned short*)p; p += ((size_t)E * 2 + 15) & ~15ull;
    unsigned* csr = (unsigned*)p; p += (size_t)E * 4;
    unsigned short* WbfT = (unsigned short*)p; p += 4 * 128 * 128 * 2;
    unsigned short* hcat = (unsigned short*)p; p += NF * 2 * 4;   // 4 bf16 slices
    float* outb = (float*)p;     p += NF * 4;                      // right after hcat (OOB-read pad)
    float* sm = (float*)p;       p += (size_t)GRAPHS * F * 4;
    float* Ag = (float*)p;       p += (size_t)GRAPHS * F * 4;

    hipMemsetAsync(d_ws, 0, zeroBytes, stream);

    int eb = (E + 255) / 256;
    int nb = (N + 255) / 256;
    int sb = (N + SCAN_B - 1) / SCAN_B;

    ushort4* hs0 = (ushort4*)(hcat);
    ushort4* hs1 = (ushort4*)(hcat + NF);
    ushort4* hs2 = (ushort4*)(hcat + 2 * NF);
    ushort4* hs3 = (ushort4*)(hcat + 3 * NF);

    deg_kernel<<<eb, 256, 0, stream>>>(ei, ew, packed, rank, E);
    dinv_start_kernel<<<nb, 256, 0, stream>>>(packed, dinv, cnt, batch, gstart, N);
    scan1_kernel<<<sb, SCAN_B, 0, stream>>>(cnt, offs, blockSums, N);
    scan2_kernel<<<1, 1024, 0, stream>>>(blockSums, sb);
    scan3_kernel<<<sb, SCAN_B, 0, stream>>>(offs, blockSums, N, E);
    f2b_kernel<<<(N * 32 + 255) / 256, 256, 0, stream>>>((const float4*)y, hs0, N * 32);
    wcvt_kernel<<<(4 * 128 * 128) / 256, 256, 0, stream>>>(tag_w, WbfT);
    scatter_kernel<<<eb, 256, 0, stream>>>(ei, ew, dinv, offs, rank, csr, E);

    int hb = (N + 7) / 8;
    hop_kernel<<<hb, 256, 0, stream>>>(hs0, hs1, offs, csr, dinv, N);
    hop_kernel<<<hb, 256, 0, stream>>>(hs1, hs2, offs, csr, dinv, N);
    hop_kernel<<<hb, 256, 0, stream>>>(hs2, hs3, offs, csr, dinv, N);

    gemm_kernel<<<(N + 63) / 64, 256, 0, stream>>>(hcat, WbfT, tag_b, outb, N, NF);

    stats_kernel<<<(N + STAT_NODES - 1) / STAT_NODES, 256, 0, stream>>>(outb, batch, S1, S2, N);
    finalize_kernel<<<(GRAPHS * F + 255) / 256, 256, 0, stream>>>(S1, S2, gstart, gnw, gms, sm, Ag, GRAPHS * F);
    final_kernel<<<(N * 32 + 255) / 256, 256, 0, stream>>>((const float4*)y, (const float4*)outb,
                                                           batch, (const float4*)sm, (const float4*)Ag,
                                                           (const float4*)gnb, (float4*)res, N);
}

// Round 6
// 299.591 us; speedup vs baseline: 2.4160x; 1.1935x over previous
//
#include <hip/hip_runtime.h>

#define F 128
#define GRAPHS 64
#define GN_EPS 1e-5f
#define SCAN_B 256

typedef short short8 __attribute__((ext_vector_type(8)));
typedef float f32x4 __attribute__((ext_vector_type(4)));

__device__ __forceinline__ unsigned short f2b(float f) {      // fp32 -> bf16 RNE
    unsigned u = __float_as_uint(f);
    unsigned r = (u + 0x7fffu + ((u >> 16) & 1u)) >> 16;
    return (unsigned short)r;
}
__device__ __forceinline__ float b2f(unsigned short h) {      // bf16 -> fp32
    return __uint_as_float(((unsigned)h) << 16);
}

// ---------------- degree + count in ONE packed 64-bit atomic per edge --------------
// bits [0,40): sum of w quantized at 2^24; bits [40,64): edge count.
// The RETURN value's count field is this edge's rank within its dst segment.
__global__ void deg_kernel(const int* __restrict__ ei, const float* __restrict__ w,
                           unsigned long long* __restrict__ packed,
                           unsigned short* __restrict__ rank, int E) {
    int e = blockIdx.x * blockDim.x + threadIdx.x;
    if (e >= E) return;
    int dst = ei[E + e];
    unsigned q = (unsigned)(w[e] * 16777216.0f + 0.5f);
    unsigned long long old = atomicAdd(&packed[dst], (1ull << 40) | (unsigned long long)q);
    rank[e] = (unsigned short)(old >> 40);
}

// ---------------- decode packed -> dinv + cnt; graph starts (batch sorted) --------
__global__ void dinv_start_kernel(const unsigned long long* __restrict__ packed,
                                  float* __restrict__ dinv, int* __restrict__ cnt,
                                  const int* __restrict__ batch, int* __restrict__ gstart, int n) {
    int i = blockIdx.x * blockDim.x + threadIdx.x;
    if (i >= n) return;
    unsigned long long p = packed[i];
    cnt[i] = (int)(p >> 40);
    float d = (float)(p & 0xFFFFFFFFFFull) * 5.9604644775390625e-8f;  // / 2^24
    dinv[i] = (d > 0.f) ? rsqrtf(fmaxf(d, 1e-30f)) : 0.f;
    int b = batch[i];
    if (i == 0) {
        for (int g = 0; g <= b; ++g) gstart[g] = 0;
    } else {
        int bp = batch[i - 1];
        for (int g = bp + 1; g <= b; ++g) gstart[g] = i;
    }
    if (i == n - 1) {
        for (int g = b + 1; g <= GRAPHS; ++g) gstart[g] = n;
    }
}

// ---------------- exclusive scan of cnt -> offsets (3 phases) ----------------
__global__ void scan1_kernel(const int* __restrict__ cnt, int* __restrict__ excl,
                             int* __restrict__ blockSums, int n) {
    __shared__ int s[SCAN_B];
    int i = blockIdx.x * SCAN_B + threadIdx.x;
    int v = (i < n) ? cnt[i] : 0;
    s[threadIdx.x] = v;
    __syncthreads();
    for (int off = 1; off < SCAN_B; off <<= 1) {
        int t = (threadIdx.x >= off) ? s[threadIdx.x - off] : 0;
        __syncthreads();
        s[threadIdx.x] += t;
        __syncthreads();
    }
    if (i < n) excl[i] = s[threadIdx.x] - v;
    if (threadIdx.x == SCAN_B - 1) blockSums[blockIdx.x] = s[SCAN_B - 1];
}

__global__ void scan2_kernel(int* __restrict__ blockSums, int nb) {
    __shared__ int s[1024];
    int v = (threadIdx.x < nb) ? blockSums[threadIdx.x] : 0;
    s[threadIdx.x] = v;
    __syncthreads();
    for (int off = 1; off < 1024; off <<= 1) {
        int t = (threadIdx.x >= off) ? s[threadIdx.x - off] : 0;
        __syncthreads();
        s[threadIdx.x] += t;
        __syncthreads();
    }
    if (threadIdx.x < nb) blockSums[threadIdx.x] = s[threadIdx.x] - v;
}

__global__ void scan3_kernel(int* __restrict__ offs, const int* __restrict__ blockSums,
                             int n, int total) {
    int i = blockIdx.x * SCAN_B + threadIdx.x;
    if (i < n) offs[i] += blockSums[blockIdx.x];
    if (i == 0) offs[n] = total;
}

// ---------------- scatter edges into CSR: NO atomics, single 4B write per edge ------
// entry = (src:16 | bf16(dinv[src]*w):16)
__global__ void scatter_kernel(const int* __restrict__ ei, const float* __restrict__ w,
                               const float* __restrict__ dinv, const int* __restrict__ offs,
                               const unsigned short* __restrict__ rank,
                               unsigned* __restrict__ csr, int E) {
    int e = blockIdx.x * blockDim.x + threadIdx.x;
    if (e >= E) return;
    int s = ei[e];
    int d = ei[E + e];
    unsigned v = ((unsigned)s << 16) | (unsigned)f2b(dinv[s] * w[e]);
    csr[offs[d] + (int)rank[e]] = v;
}

// ---------------- fp32 -> bf16 row conversion (y -> hcat slice 0) ----------------
__global__ void f2b_kernel(const float4* __restrict__ in, ushort4* __restrict__ out, int n4) {
    int i = blockIdx.x * blockDim.x + threadIdx.x;
    if (i >= n4) return;
    float4 v = in[i];
    out[i] = make_ushort4(f2b(v.x), f2b(v.y), f2b(v.z), f2b(v.w));
}

// ---------------- tag_w fp32 [4][k=128][n=128] -> MFMA B-fragment order bf16 --------
// Wf[seg][kb][wc][nt][lane][j] : k = kb*32 + (lane>>4)*8 + j, n = wc*64 + nt*16 + (lane&15)
// so a wave's B-frag load is lane-contiguous (lane*8 shorts = 16 B/lane).
__global__ void wcvt_kernel(const float* __restrict__ w, unsigned short* __restrict__ wt) {
    int i = blockIdx.x * blockDim.x + threadIdx.x;   // over 4*128*128 = 65536
    int seg = i >> 14;
    int r = i & 16383;
    int kb = r >> 12;
    int wc = (r >> 11) & 1;
    int nt = (r >> 9) & 3;
    int lane = (r >> 3) & 63;
    int j = i & 7;
    int k = kb * 32 + (lane >> 4) * 8 + j;
    int n = wc * 64 + nt * 16 + (lane & 15);
    wt[i] = f2b(w[seg * 16384 + k * 128 + n]);
}

// ---------------- one hop: node-per-wave, 4 edges/iter, 16B gathers ----------------
// lane = g*16 + fl : group g handles edge j+g, fl indexes feature chunk fl*8..fl*8+7.
// Cross-group combine via shfl_xor(16), shfl_xor(32).
__global__ __launch_bounds__(256) void hop_kernel(const unsigned short* __restrict__ hin,
                                                  unsigned short* __restrict__ hout,
                                                  const int* __restrict__ offs,
                                                  const unsigned* __restrict__ csr,
                                                  const float* __restrict__ dinv, int n) {
    int lane = threadIdx.x & 63;
    int node = blockIdx.x * 4 + (threadIdx.x >> 6);
    if (node >= n) return;
    int g = lane >> 4, fl = lane & 15;
    int e0 = offs[node], e1 = offs[node + 1];
    float acc[8] = {};
    for (int j = e0; j < e1; j += 4) {
        int e = j + g;
        bool valid = e < e1;
        unsigned ed = csr[valid ? e : (e1 - 1)];
        float wv = valid ? b2f((unsigned short)(ed & 0xffffu)) : 0.f;
        short8 hv = *(const short8*)(hin + (size_t)(ed >> 16) * 128 + fl * 8);
        #pragma unroll
        for (int k = 0; k < 8; ++k)
            acc[k] += wv * b2f((unsigned short)hv[k]);
    }
    #pragma unroll
    for (int k = 0; k < 8; ++k) {
        acc[k] += __shfl_xor(acc[k], 16);
        acc[k] += __shfl_xor(acc[k], 32);
    }
    if (lane < 16) {
        float dd = dinv[node];
        short8 o;
        #pragma unroll
        for (int k = 0; k < 8; ++k) o[k] = (short)f2b(acc[k] * dd);
        *(short8*)(hout + (size_t)node * 128 + fl * 8) = o;
    }
}

// ---------------- fused GEMM: outb[N,128] = [y|h1|h2|h3] @ [W0;W1;W2;W3] + bias ------
// bf16 MFMA 16x16x32, 4 waves in 2x2 grid, M-tile 64. A staged wave-privately in LDS
// (8 KB/wave, XOR-swizzled -> 2-way-free ds_read_b128, NO __syncthreads). B read from
// fragment-ordered Wf (lane-contiguous, L2-hot).
__global__ __launch_bounds__(256) void gemm_kernel(const unsigned short* __restrict__ hcat,
                                                   const unsigned short* __restrict__ Wf,
                                                   const float* __restrict__ bias,
                                                   float* __restrict__ outb,
                                                   int M, size_t NF) {
    __shared__ unsigned short As[4][4096];   // 8 KB per wave, wave-private
    int lane = threadIdx.x & 63;
    int wid = threadIdx.x >> 6;
    int wr = wid & 1, wc = wid >> 1;
    int quad = lane >> 4, l15 = lane & 15;
    int row0 = blockIdx.x * 64;
    unsigned short* myA = As[wid];
    f32x4 acc[2][4] = {};

    for (int s = 0; s < 4; ++s) {
        const unsigned short* Aseg = hcat + (size_t)s * NF;
        // stage 32 rows x 128 k (8 KB) coalesced: 8 x 1KB wave-loads
        short8 stg[8];
        #pragma unroll
        for (int i = 0; i < 8; ++i) {
            int flat = i * 64 + lane;
            int r = flat >> 4, c = flat & 15;
            stg[i] = *(const short8*)(Aseg + (size_t)(row0 + wr * 32 + r) * 128 + c * 8);
        }
        #pragma unroll
        for (int i = 0; i < 8; ++i) {
            int flat = i * 64 + lane;
            int r = flat >> 4, c = flat & 15;
            *(short8*)&myA[(r * 16 + (c ^ (r & 15))) * 8] = stg[i];
        }
        #pragma unroll
        for (int kb = 0; kb < 4; ++kb) {
            int swz = ((kb * 4 + quad) ^ l15) * 8;
            short8 a0 = *(short8*)&myA[l15 * 128 + swz];
            short8 a1 = *(short8*)&myA[(16 + l15) * 128 + swz];
            const unsigned short* bb = Wf + (size_t)(((s * 4 + kb) * 2 + wc) * 4) * 512 + lane * 8;
            short8 b0 = *(const short8*)(bb + 0 * 512);
            short8 b1 = *(const short8*)(bb + 1 * 512);
            short8 b2 = *(const short8*)(bb + 2 * 512);
            short8 b3 = *(const short8*)(bb + 3 * 512);
            acc[0][0] = __builtin_amdgcn_mfma_f32_16x16x32_bf16(a0, b0, acc[0][0], 0, 0, 0);
            acc[0][1] = __builtin_amdgcn_mfma_f32_16x16x32_bf16(a0, b1, acc[0][1], 0, 0, 0);
            acc[0][2] = __builtin_amdgcn_mfma_f32_16x16x32_bf16(a0, b2, acc[0][2], 0, 0, 0);
            acc[0][3] = __builtin_amdgcn_mfma_f32_16x16x32_bf16(a0, b3, acc[0][3], 0, 0, 0);
            acc[1][0] = __builtin_amdgcn_mfma_f32_16x16x32_bf16(a1, b0, acc[1][0], 0, 0, 0);
            acc[1][1] = __builtin_amdgcn_mfma_f32_16x16x32_bf16(a1, b1, acc[1][1], 0, 0, 0);
            acc[1][2] = __builtin_amdgcn_mfma_f32_16x16x32_bf16(a1, b2, acc[1][2], 0, 0, 0);
            acc[1][3] = __builtin_amdgcn_mfma_f32_16x16x32_bf16(a1, b3, acc[1][3], 0, 0, 0);
        }
    }

    #pragma unroll
    for (int mt = 0; mt < 2; ++mt) {
        #pragma unroll
        for (int r = 0; r < 4; ++r) {
            int row = row0 + wr * 32 + mt * 16 + quad * 4 + r;
            if (row < M) {
                #pragma unroll
                for (int nt = 0; nt < 4; ++nt) {
                    int col = wc * 64 + nt * 16 + l15;
                    outb[(size_t)row * 128 + col] = acc[mt][nt][r] + bias[col];
                }
            }
        }
    }
}

// ---------------- per-graph sums S1, S2 (parallel; sorted-batch flush trick) ----------
#define STAT_NODES 32
__global__ __launch_bounds__(256) void stats_kernel(const float* __restrict__ out,
                                                    const int* __restrict__ batch,
                                                    float* __restrict__ S1, float* __restrict__ S2,
                                                    int n) {
    int f = threadIdx.x & 127;
    int par = threadIdx.x >> 7;
    int base = blockIdx.x * STAT_NODES;
    int n1 = min(base + STAT_NODES, n);
    int i0 = base + par;
    if (i0 >= n1) return;
    float s1 = 0.f, s2 = 0.f;
    int curg = batch[i0];
    for (int i = i0; i < n1; i += 2) {
        int g = batch[i];
        if (g != curg) {
            atomicAdd(&S1[curg * F + f], s1);
            atomicAdd(&S2[curg * F + f], s2);
            s1 = 0.f; s2 = 0.f; curg = g;
        }
        float v = out[(size_t)i * F + f];
        s1 += v; s2 += v * v;
    }
    atomicAdd(&S1[curg * F + f], s1);
    atomicAdd(&S2[curg * F + f], s2);
}

// ---------------- finalize mean/var -> sm = s*mean, Ag = gnw * rsqrt(var+eps) --------
__global__ void finalize_kernel(const float* __restrict__ S1, const float* __restrict__ S2,
                                const int* __restrict__ gstart, const float* __restrict__ gnw,
                                const float* __restrict__ gms,
                                float* __restrict__ sm, float* __restrict__ Ag, int GF) {
    int i = blockIdx.x * blockDim.x + threadIdx.x;
    if (i >= GF) return;
    int f = i & (F - 1);
    int g = i >> 7;
    float c = fmaxf((float)(gstart[g + 1] - gstart[g]), 1.f);
    float mean = S1[i] / c;
    float e2 = S2[i] / c;
    float s = gms[f];
    float var = e2 - 2.f * s * mean * mean + s * s * mean * mean;
    sm[i] = s * mean;
    Ag[i] = gnw[f] * rsqrtf(var + GN_EPS);
}

// ---------------- fused normalize + relu + residual ----------------
__global__ void final_kernel(const float4* __restrict__ y, const float4* __restrict__ out,
                             const int* __restrict__ batch, const float4* __restrict__ sm,
                             const float4* __restrict__ Ag, const float4* __restrict__ gnb,
                             float4* __restrict__ res, int n) {
    int idx = blockIdx.x * blockDim.x + threadIdx.x;
    if (idx >= n * 32) return;
    int node = idx >> 5;
    int q = idx & 31;
    int g = batch[node];
    float4 o = out[idx];
    float4 yv = y[idx];
    float4 m = sm[g * 32 + q];
    float4 a = Ag[g * 32 + q];
    float4 b = gnb[q];
    float4 r;
    r.x = yv.x + fmaxf(0.f, (o.x - m.x) * a.x + b.x);
    r.y = yv.y + fmaxf(0.f, (o.y - m.y) * a.y + b.y);
    r.z = yv.z + fmaxf(0.f, (o.z - m.z) * a.z + b.z);
    r.w = yv.w + fmaxf(0.f, (o.w - m.w) * a.w + b.w);
    res[idx] = r;
}

extern "C" void kernel_launch(void* const* d_in, const int* in_sizes, int n_in,
                              void* d_out, int out_size, void* d_ws, size_t ws_size,
                              hipStream_t stream) {
    const float* y     = (const float*)d_in[0];
    const int*   ei    = (const int*)d_in[1];
    const float* ew    = (const float*)d_in[2];
    const int*   batch = (const int*)d_in[3];
    const float* tag_w = (const float*)d_in[4];
    const float* tag_b = (const float*)d_in[5];
    const float* gnw   = (const float*)d_in[6];
    const float* gnb   = (const float*)d_in[7];
    const float* gms   = (const float*)d_in[8];
    float* res = (float*)d_out;

    const int N = in_sizes[0] / F;
    const int E = in_sizes[1] / 2;
    const size_t NF = (size_t)N * F;

    // ---- workspace layout (zero-init region first, one memset) ----
    char* p = (char*)d_ws;
    unsigned long long* packed = (unsigned long long*)p; p += (size_t)N * 8;
    float* S1 = (float*)p;       p += (size_t)GRAPHS * F * 4;
    float* S2 = (float*)p;       p += (size_t)GRAPHS * F * 4;
    size_t zeroBytes = (size_t)(p - (char*)d_ws);
    int*   gstart = (int*)p;     p += 512;
    float* dinv = (float*)p;     p += (size_t)N * 4;
    int*   cnt = (int*)p;        p += (size_t)N * 4;
    int*   offs = (int*)p;       p += (size_t)(N + 4) * 4;
    int*   blockSums = (int*)p;  p += 4096;
    unsigned short* rank = (unsigned short*)p; p += ((size_t)E * 2 + 15) & ~15ull;
    unsigned* csr = (unsigned*)p; p += (size_t)E * 4;
    unsigned short* Wf = (unsigned short*)p; p += 4 * 128 * 128 * 2;
    unsigned short* hcat = (unsigned short*)p; p += NF * 2 * 4;   // 4 bf16 slices
    float* outb = (float*)p;     p += NF * 4;                      // right after hcat (OOB-read pad)
    float* sm = (float*)p;       p += (size_t)GRAPHS * F * 4;
    float* Ag = (float*)p;       p += (size_t)GRAPHS * F * 4;

    hipMemsetAsync(d_ws, 0, zeroBytes, stream);

    int eb = (E + 255) / 256;
    int nb = (N + 255) / 256;
    int sb = (N + SCAN_B - 1) / SCAN_B;

    unsigned short* hs0 = hcat;
    unsigned short* hs1 = hcat + NF;
    unsigned short* hs2 = hcat + 2 * NF;
    unsigned short* hs3 = hcat + 3 * NF;

    deg_kernel<<<eb, 256, 0, stream>>>(ei, ew, packed, rank, E);
    dinv_start_kernel<<<nb, 256, 0, stream>>>(packed, dinv, cnt, batch, gstart, N);
    scan1_kernel<<<sb, SCAN_B, 0, stream>>>(cnt, offs, blockSums, N);
    scan2_kernel<<<1, 1024, 0, stream>>>(blockSums, sb);
    scan3_kernel<<<sb, SCAN_B, 0, stream>>>(offs, blockSums, N, E);
    f2b_kernel<<<(N * 32 + 255) / 256, 256, 0, stream>>>((const float4*)y, (ushort4*)hs0, N * 32);
    wcvt_kernel<<<(4 * 128 * 128) / 256, 256, 0, stream>>>(tag_w, Wf);
    scatter_kernel<<<eb, 256, 0, stream>>>(ei, ew, dinv, offs, rank, csr, E);

    int hb = (N + 3) / 4;
    hop_kernel<<<hb, 256, 0, stream>>>(hs0, hs1, offs, csr, dinv, N);
    hop_kernel<<<hb, 256, 0, stream>>>(hs1, hs2, offs, csr, dinv, N);
    hop_kernel<<<hb, 256, 0, stream>>>(hs2, hs3, offs, csr, dinv, N);

    gemm_kernel<<<(N + 63) / 64, 256, 0, stream>>>(hcat, Wf, tag_b, outb, N, NF);

    stats_kernel<<<(N + STAT_NODES - 1) / STAT_NODES, 256, 0, stream>>>(outb, batch, S1, S2, N);
    finalize_kernel<<<(GRAPHS * F + 255) / 256, 256, 0, stream>>>(S1, S2, gstart, gnw, gms, sm, Ag, GRAPHS * F);
    final_kernel<<<(N * 32 + 255) / 256, 256, 0, stream>>>((const float4*)y, (const float4*)outb,
                                                           batch, (const float4*)sm, (const float4*)Ag,
                                                           (const float4*)gnb, (float4*)res, N);
}

// Round 7
// 265.574 us; speedup vs baseline: 2.7254x; 1.1281x over previous
//
#include <hip/hip_runtime.h>

#define F 128
#define GRAPHS 64
#define GN_EPS 1e-5f
#define SCAN_B 256

typedef short short8 __attribute__((ext_vector_type(8)));
typedef float f32x4 __attribute__((ext_vector_type(4)));

__device__ __forceinline__ unsigned short f2b(float f) {      // fp32 -> bf16 RNE
    unsigned u = __float_as_uint(f);
    unsigned r = (u + 0x7fffu + ((u >> 16) & 1u)) >> 16;
    return (unsigned short)r;
}
__device__ __forceinline__ float b2f(unsigned short h) {      // bf16 -> fp32
    return __uint_as_float(((unsigned)h) << 16);
}

// ---------------- fused front-end: [deg | f2b | wcvt] (all read only inputs) --------
// deg: degree+count in ONE packed 64-bit atomic per edge; atomic return = edge's rank.
// f2b: y fp32 -> bf16 (hcat slice 0).
// wcvt: tag_w fp32 [4][k][n] -> MFMA B-fragment-ordered bf16.
__global__ void prep_kernel(const int* __restrict__ ei, const float* __restrict__ ew,
                            unsigned long long* __restrict__ packed,
                            unsigned short* __restrict__ rank, int E, int ebl,
                            const float4* __restrict__ y, ushort4* __restrict__ hs0,
                            int n4, int fbl,
                            const float* __restrict__ tw, unsigned short* __restrict__ wf) {
    int b = blockIdx.x;
    if (b < ebl) {                                   // ---- deg ----
        int e = b * 256 + threadIdx.x;
        if (e < E) {
            int dst = ei[E + e];
            unsigned q = (unsigned)(ew[e] * 16777216.0f + 0.5f);
            unsigned long long old =
                atomicAdd(&packed[dst], (1ull << 40) | (unsigned long long)q);
            rank[e] = (unsigned short)(old >> 40);
        }
    } else if (b < ebl + fbl) {                      // ---- f2b ----
        int i = (b - ebl) * 256 + threadIdx.x;
        if (i < n4) {
            float4 v = y[i];
            hs0[i] = make_ushort4(f2b(v.x), f2b(v.y), f2b(v.z), f2b(v.w));
        }
    } else {                                         // ---- wcvt ----
        int i = (b - ebl - fbl) * 256 + threadIdx.x; // over 4*128*128 = 65536
        int seg = i >> 14;
        int r = i & 16383;
        int kb = r >> 12;
        int wc = (r >> 11) & 1;
        int nt = (r >> 9) & 3;
        int lane = (r >> 3) & 63;
        int j = i & 7;
        int k = kb * 32 + (lane >> 4) * 8 + j;
        int n = wc * 64 + nt * 16 + (lane & 15);
        wf[i] = f2b(tw[seg * 16384 + k * 128 + n]);
    }
}

// ---------------- fused: decode packed -> dinv, graph starts, block-local scan ------
__global__ void node_prep_kernel(const unsigned long long* __restrict__ packed,
                                 float* __restrict__ dinv, const int* __restrict__ batch,
                                 int* __restrict__ gstart, int* __restrict__ excl,
                                 int* __restrict__ blockSums, int n) {
    __shared__ int s[SCAN_B];
    int i = blockIdx.x * SCAN_B + threadIdx.x;
    int v = 0;
    if (i < n) {
        unsigned long long p = packed[i];
        v = (int)(p >> 40);
        float d = (float)(p & 0xFFFFFFFFFFull) * 5.9604644775390625e-8f;  // / 2^24
        dinv[i] = (d > 0.f) ? rsqrtf(fmaxf(d, 1e-30f)) : 0.f;
        int b = batch[i];
        if (i == 0) {
            for (int g = 0; g <= b; ++g) gstart[g] = 0;
        } else {
            int bp = batch[i - 1];
            for (int g = bp + 1; g <= b; ++g) gstart[g] = i;
        }
        if (i == n - 1) {
            for (int g = b + 1; g <= GRAPHS; ++g) gstart[g] = n;
        }
    }
    s[threadIdx.x] = v;
    __syncthreads();
    for (int off = 1; off < SCAN_B; off <<= 1) {
        int t = (threadIdx.x >= off) ? s[threadIdx.x - off] : 0;
        __syncthreads();
        s[threadIdx.x] += t;
        __syncthreads();
    }
    if (i < n) excl[i] = s[threadIdx.x] - v;
    if (threadIdx.x == SCAN_B - 1) blockSums[blockIdx.x] = s[SCAN_B - 1];
}

__global__ void scan2_kernel(int* __restrict__ blockSums, int nb) {
    __shared__ int s[1024];
    int v = (threadIdx.x < nb) ? blockSums[threadIdx.x] : 0;
    s[threadIdx.x] = v;
    __syncthreads();
    for (int off = 1; off < 1024; off <<= 1) {
        int t = (threadIdx.x >= off) ? s[threadIdx.x - off] : 0;
        __syncthreads();
        s[threadIdx.x] += t;
        __syncthreads();
    }
    if (threadIdx.x < nb) blockSums[threadIdx.x] = s[threadIdx.x] - v;
}

__global__ void scan3_kernel(int* __restrict__ offs, const int* __restrict__ blockSums,
                             int n, int total) {
    int i = blockIdx.x * SCAN_B + threadIdx.x;
    if (i < n) offs[i] += blockSums[blockIdx.x];
    if (i == 0) offs[n] = total;
}

// ---------------- scatter edges into CSR: NO atomics, single 4B write per edge ------
// entry = (src:16 | bf16(dinv[src]*w):16)
__global__ void scatter_kernel(const int* __restrict__ ei, const float* __restrict__ w,
                               const float* __restrict__ dinv, const int* __restrict__ offs,
                               const unsigned short* __restrict__ rank,
                               unsigned* __restrict__ csr, int E) {
    int e = blockIdx.x * blockDim.x + threadIdx.x;
    if (e >= E) return;
    int s = ei[e];
    int d = ei[E + e];
    unsigned v = ((unsigned)s << 16) | (unsigned)f2b(dinv[s] * w[e]);
    csr[offs[d] + (int)rank[e]] = v;
}

// ---------------- one hop: node-per-wave, 8 edges in flight, 16B gathers ------------
// 16-lane group g handles edges j+2g, j+2g+1 -> 2 independent gather chains/group.
__global__ __launch_bounds__(256) void hop_kernel(const unsigned short* __restrict__ hin,
                                                  unsigned short* __restrict__ hout,
                                                  const int* __restrict__ offs,
                                                  const unsigned* __restrict__ csr,
                                                  const float* __restrict__ dinv, int n) {
    int lane = threadIdx.x & 63;
    int node = blockIdx.x * 4 + (threadIdx.x >> 6);
    if (node >= n) return;
    int g = lane >> 4, fl = lane & 15;
    int e0 = offs[node], e1 = offs[node + 1];
    float acc[8] = {};
    for (int j = e0; j < e1; j += 8) {
        int ea = j + g * 2, eb = ea + 1;
        bool va = ea < e1, vb = eb < e1;
        unsigned eda = csr[va ? ea : (e1 - 1)];
        unsigned edb = csr[vb ? eb : (e1 - 1)];
        float wa = va ? b2f((unsigned short)(eda & 0xffffu)) : 0.f;
        float wb = vb ? b2f((unsigned short)(edb & 0xffffu)) : 0.f;
        short8 ha = *(const short8*)(hin + (size_t)(eda >> 16) * 128 + fl * 8);
        short8 hb = *(const short8*)(hin + (size_t)(edb >> 16) * 128 + fl * 8);
        #pragma unroll
        for (int k = 0; k < 8; ++k)
            acc[k] += wa * b2f((unsigned short)ha[k]) + wb * b2f((unsigned short)hb[k]);
    }
    #pragma unroll
    for (int k = 0; k < 8; ++k) {
        acc[k] += __shfl_xor(acc[k], 16);
        acc[k] += __shfl_xor(acc[k], 32);
    }
    if (lane < 16) {
        float dd = dinv[node];
        short8 o;
        #pragma unroll
        for (int k = 0; k < 8; ++k) o[k] = (short)f2b(acc[k] * dd);
        *(short8*)(hout + (size_t)node * 128 + fl * 8) = o;
    }
}

// ---------------- fused GEMM: outb[N,128] = [y|h1|h2|h3] @ [W0;W1;W2;W3] + bias ------
// bf16 MFMA 16x16x32, 4 waves in 2x2 grid, M-tile 64. A staged wave-privately in LDS
// (XOR-swizzled ds_read_b128, no __syncthreads). B from fragment-ordered Wf (L2-hot).
__global__ __launch_bounds__(256) void gemm_kernel(const unsigned short* __restrict__ hcat,
                                                   const unsigned short* __restrict__ Wf,
                                                   const float* __restrict__ bias,
                                                   float* __restrict__ outb,
                                                   int M, size_t NF) {
    __shared__ unsigned short As[4][4096];   // 8 KB per wave, wave-private
    int lane = threadIdx.x & 63;
    int wid = threadIdx.x >> 6;
    int wr = wid & 1, wc = wid >> 1;
    int quad = lane >> 4, l15 = lane & 15;
    int row0 = blockIdx.x * 64;
    unsigned short* myA = As[wid];
    f32x4 acc[2][4] = {};

    for (int s = 0; s < 4; ++s) {
        const unsigned short* Aseg = hcat + (size_t)s * NF;
        short8 stg[8];
        #pragma unroll
        for (int i = 0; i < 8; ++i) {
            int flat = i * 64 + lane;
            int r = flat >> 4, c = flat & 15;
            stg[i] = *(const short8*)(Aseg + (size_t)(row0 + wr * 32 + r) * 128 + c * 8);
        }
        #pragma unroll
        for (int i = 0; i < 8; ++i) {
            int flat = i * 64 + lane;
            int r = flat >> 4, c = flat & 15;
            *(short8*)&myA[(r * 16 + (c ^ (r & 15))) * 8] = stg[i];
        }
        #pragma unroll
        for (int kb = 0; kb < 4; ++kb) {
            int swz = ((kb * 4 + quad) ^ l15) * 8;
            short8 a0 = *(short8*)&myA[l15 * 128 + swz];
            short8 a1 = *(short8*)&myA[(16 + l15) * 128 + swz];
            const unsigned short* bb = Wf + (size_t)(((s * 4 + kb) * 2 + wc) * 4) * 512 + lane * 8;
            short8 b0 = *(const short8*)(bb + 0 * 512);
            short8 b1 = *(const short8*)(bb + 1 * 512);
            short8 b2 = *(const short8*)(bb + 2 * 512);
            short8 b3 = *(const short8*)(bb + 3 * 512);
            acc[0][0] = __builtin_amdgcn_mfma_f32_16x16x32_bf16(a0, b0, acc[0][0], 0, 0, 0);
            acc[0][1] = __builtin_amdgcn_mfma_f32_16x16x32_bf16(a0, b1, acc[0][1], 0, 0, 0);
            acc[0][2] = __builtin_amdgcn_mfma_f32_16x16x32_bf16(a0, b2, acc[0][2], 0, 0, 0);
            acc[0][3] = __builtin_amdgcn_mfma_f32_16x16x32_bf16(a0, b3, acc[0][3], 0, 0, 0);
            acc[1][0] = __builtin_amdgcn_mfma_f32_16x16x32_bf16(a1, b0, acc[1][0], 0, 0, 0);
            acc[1][1] = __builtin_amdgcn_mfma_f32_16x16x32_bf16(a1, b1, acc[1][1], 0, 0, 0);
            acc[1][2] = __builtin_amdgcn_mfma_f32_16x16x32_bf16(a1, b2, acc[1][2], 0, 0, 0);
            acc[1][3] = __builtin_amdgcn_mfma_f32_16x16x32_bf16(a1, b3, acc[1][3], 0, 0, 0);
        }
    }

    #pragma unroll
    for (int mt = 0; mt < 2; ++mt) {
        #pragma unroll
        for (int r = 0; r < 4; ++r) {
            int row = row0 + wr * 32 + mt * 16 + quad * 4 + r;
            if (row < M) {
                #pragma unroll
                for (int nt = 0; nt < 4; ++nt) {
                    int col = wc * 64 + nt * 16 + l15;
                    outb[(size_t)row * 128 + col] = acc[mt][nt][r] + bias[col];
                }
            }
        }
    }
}

// ---------------- per-graph sums S1, S2 (parallel; sorted-batch flush trick) ----------
#define STAT_NODES 32
__global__ __launch_bounds__(256) void stats_kernel(const float* __restrict__ out,
                                                    const int* __restrict__ batch,
                                                    float* __restrict__ S1, float* __restrict__ S2,
                                                    int n) {
    int f = threadIdx.x & 127;
    int par = threadIdx.x >> 7;
    int base = blockIdx.x * STAT_NODES;
    int n1 = min(base + STAT_NODES, n);
    int i0 = base + par;
    if (i0 >= n1) return;
    float s1 = 0.f, s2 = 0.f;
    int curg = batch[i0];
    for (int i = i0; i < n1; i += 2) {
        int g = batch[i];
        if (g != curg) {
            atomicAdd(&S1[curg * F + f], s1);
            atomicAdd(&S2[curg * F + f], s2);
            s1 = 0.f; s2 = 0.f; curg = g;
        }
        float v = out[(size_t)i * F + f];
        s1 += v; s2 += v * v;
    }
    atomicAdd(&S1[curg * F + f], s1);
    atomicAdd(&S2[curg * F + f], s2);
}

// ---------------- finalize mean/var -> sm = s*mean, Ag = gnw * rsqrt(var+eps) --------
__global__ void finalize_kernel(const float* __restrict__ S1, const float* __restrict__ S2,
                                const int* __restrict__ gstart, const float* __restrict__ gnw,
                                const float* __restrict__ gms,
                                float* __restrict__ sm, float* __restrict__ Ag, int GF) {
    int i = blockIdx.x * blockDim.x + threadIdx.x;
    if (i >= GF) return;
    int f = i & (F - 1);
    int g = i >> 7;
    float c = fmaxf((float)(gstart[g + 1] - gstart[g]), 1.f);
    float mean = S1[i] / c;
    float e2 = S2[i] / c;
    float s = gms[f];
    float var = e2 - 2.f * s * mean * mean + s * s * mean * mean;
    sm[i] = s * mean;
    Ag[i] = gnw[f] * rsqrtf(var + GN_EPS);
}

// ---------------- fused normalize + relu + residual ----------------
__global__ void final_kernel(const float4* __restrict__ y, const float4* __restrict__ out,
                             const int* __restrict__ batch, const float4* __restrict__ sm,
                             const float4* __restrict__ Ag, const float4* __restrict__ gnb,
                             float4* __restrict__ res, int n) {
    int idx = blockIdx.x * blockDim.x + threadIdx.x;
    if (idx >= n * 32) return;
    int node = idx >> 5;
    int q = idx & 31;
    int g = batch[node];
    float4 o = out[idx];
    float4 yv = y[idx];
    float4 m = sm[g * 32 + q];
    float4 a = Ag[g * 32 + q];
    float4 b = gnb[q];
    float4 r;
    r.x = yv.x + fmaxf(0.f, (o.x - m.x) * a.x + b.x);
    r.y = yv.y + fmaxf(0.f, (o.y - m.y) * a.y + b.y);
    r.z = yv.z + fmaxf(0.f, (o.z - m.z) * a.z + b.z);
    r.w = yv.w + fmaxf(0.f, (o.w - m.w) * a.w + b.w);
    res[idx] = r;
}

extern "C" void kernel_launch(void* const* d_in, const int* in_sizes, int n_in,
                              void* d_out, int out_size, void* d_ws, size_t ws_size,
                              hipStream_t stream) {
    const float* y     = (const float*)d_in[0];
    const int*   ei    = (const int*)d_in[1];
    const float* ew    = (const float*)d_in[2];
    const int*   batch = (const int*)d_in[3];
    const float* tag_w = (const float*)d_in[4];
    const float* tag_b = (const float*)d_in[5];
    const float* gnw   = (const float*)d_in[6];
    const float* gnb   = (const float*)d_in[7];
    const float* gms   = (const float*)d_in[8];
    float* res = (float*)d_out;

    const int N = in_sizes[0] / F;
    const int E = in_sizes[1] / 2;
    const size_t NF = (size_t)N * F;

    // ---- workspace layout (zero-init region first, one memset) ----
    char* p = (char*)d_ws;
    unsigned long long* packed = (unsigned long long*)p; p += (size_t)N * 8;
    float* S1 = (float*)p;       p += (size_t)GRAPHS * F * 4;
    float* S2 = (float*)p;       p += (size_t)GRAPHS * F * 4;
    size_t zeroBytes = (size_t)(p - (char*)d_ws);
    int*   gstart = (int*)p;     p += 512;
    float* dinv = (float*)p;     p += (size_t)N * 4;
    int*   offs = (int*)p;       p += (size_t)(N + 4) * 4;
    int*   blockSums = (int*)p;  p += 4096;
    unsigned short* rank = (unsigned short*)p; p += ((size_t)E * 2 + 15) & ~15ull;
    unsigned* csr = (unsigned*)p; p += (size_t)E * 4;
    unsigned short* Wf = (unsigned short*)p; p += 4 * 128 * 128 * 2;
    unsigned short* hcat = (unsigned short*)p; p += NF * 2 * 4;   // 4 bf16 slices
    float* outb = (float*)p;     p += NF * 4;                      // right after hcat (OOB-read pad)
    float* sm = (float*)p;       p += (size_t)GRAPHS * F * 4;
    float* Ag = (float*)p;       p += (size_t)GRAPHS * F * 4;

    hipMemsetAsync(d_ws, 0, zeroBytes, stream);

    int eb = (E + 255) / 256;
    int sb = (N + SCAN_B - 1) / SCAN_B;
    int n4 = N * 32;
    int fb = (n4 + 255) / 256;
    int wb = (4 * 128 * 128) / 256;

    unsigned short* hs0 = hcat;
    unsigned short* hs1 = hcat + NF;
    unsigned short* hs2 = hcat + 2 * NF;
    unsigned short* hs3 = hcat + 3 * NF;

    prep_kernel<<<eb + fb + wb, 256, 0, stream>>>(ei, ew, packed, rank, E, eb,
                                                  (const float4*)y, (ushort4*)hs0, n4, fb,
                                                  tag_w, Wf);
    node_prep_kernel<<<sb, SCAN_B, 0, stream>>>(packed, dinv, batch, gstart, offs, blockSums, N);
    scan2_kernel<<<1, 1024, 0, stream>>>(blockSums, sb);
    scan3_kernel<<<sb, SCAN_B, 0, stream>>>(offs, blockSums, N, E);
    scatter_kernel<<<eb, 256, 0, stream>>>(ei, ew, dinv, offs, rank, csr, E);

    int hb = (N + 3) / 4;
    hop_kernel<<<hb, 256, 0, stream>>>(hs0, hs1, offs, csr, dinv, N);
    hop_kernel<<<hb, 256, 0, stream>>>(hs1, hs2, offs, csr, dinv, N);
    hop_kernel<<<hb, 256, 0, stream>>>(hs2, hs3, offs, csr, dinv, N);

    gemm_kernel<<<(N + 63) / 64, 256, 0, stream>>>(hcat, Wf, tag_b, outb, N, NF);

    stats_kernel<<<(N + STAT_NODES - 1) / STAT_NODES, 256, 0, stream>>>(outb, batch, S1, S2, N);
    finalize_kernel<<<(GRAPHS * F + 255) / 256, 256, 0, stream>>>(S1, S2, gstart, gnw, gms, sm, Ag, GRAPHS * F);
    final_kernel<<<(N * 32 + 255) / 256, 256, 0, stream>>>((const float4*)y, (const float4*)outb,
                                                           batch, (const float4*)sm, (const float4*)Ag,
                                                           (const float4*)gnb, (float4*)res, N);
}

// Round 8
// 255.297 us; speedup vs baseline: 2.8351x; 1.0403x over previous
//
#include <hip/hip_runtime.h>

#define F 128
#define GRAPHS 64
#define GN_EPS 1e-5f
#define SCAN_B 256

typedef short short8 __attribute__((ext_vector_type(8)));
typedef float f32x4 __attribute__((ext_vector_type(4)));

__device__ __forceinline__ unsigned short f2b(float f) {      // fp32 -> bf16 RNE
    unsigned u = __float_as_uint(f);
    unsigned r = (u + 0x7fffu + ((u >> 16) & 1u)) >> 16;
    return (unsigned short)r;
}
__device__ __forceinline__ float b2f(unsigned short h) {      // bf16 -> fp32
    return __uint_as_float(((unsigned)h) << 16);
}

// ---------------- fused front-end: [deg | f2b | wcvt] (all read only inputs) --------
__global__ void prep_kernel(const int* __restrict__ ei, const float* __restrict__ ew,
                            unsigned long long* __restrict__ packed,
                            unsigned short* __restrict__ rank, int E, int ebl,
                            const float4* __restrict__ y, ushort4* __restrict__ hs0,
                            int n4, int fbl,
                            const float* __restrict__ tw, unsigned short* __restrict__ wf) {
    int b = blockIdx.x;
    if (b < ebl) {                                   // ---- deg ----
        int e = b * 256 + threadIdx.x;
        if (e < E) {
            int dst = ei[E + e];
            unsigned q = (unsigned)(ew[e] * 16777216.0f + 0.5f);
            unsigned long long old =
                atomicAdd(&packed[dst], (1ull << 40) | (unsigned long long)q);
            rank[e] = (unsigned short)(old >> 40);
        }
    } else if (b < ebl + fbl) {                      // ---- f2b ----
        int i = (b - ebl) * 256 + threadIdx.x;
        if (i < n4) {
            float4 v = y[i];
            hs0[i] = make_ushort4(f2b(v.x), f2b(v.y), f2b(v.z), f2b(v.w));
        }
    } else {                                         // ---- wcvt ----
        int i = (b - ebl - fbl) * 256 + threadIdx.x; // over 4*128*128 = 65536
        int seg = i >> 14;
        int r = i & 16383;
        int kb = r >> 12;
        int wc = (r >> 11) & 1;
        int nt = (r >> 9) & 3;
        int lane = (r >> 3) & 63;
        int j = i & 7;
        int k = kb * 32 + (lane >> 4) * 8 + j;
        int n = wc * 64 + nt * 16 + (lane & 15);
        wf[i] = f2b(tw[seg * 16384 + k * 128 + n]);
    }
}

// ---------------- fused: decode packed -> dinv, graph starts, block-local scan ------
__global__ void node_prep_kernel(const unsigned long long* __restrict__ packed,
                                 float* __restrict__ dinv, const int* __restrict__ batch,
                                 int* __restrict__ gstart, int* __restrict__ excl,
                                 int* __restrict__ blockSums, int n) {
    __shared__ int s[SCAN_B];
    int i = blockIdx.x * SCAN_B + threadIdx.x;
    int v = 0;
    if (i < n) {
        unsigned long long p = packed[i];
        v = (int)(p >> 40);
        float d = (float)(p & 0xFFFFFFFFFFull) * 5.9604644775390625e-8f;  // / 2^24
        dinv[i] = (d > 0.f) ? rsqrtf(fmaxf(d, 1e-30f)) : 0.f;
        int b = batch[i];
        if (i == 0) {
            for (int g = 0; g <= b; ++g) gstart[g] = 0;
        } else {
            int bp = batch[i - 1];
            for (int g = bp + 1; g <= b; ++g) gstart[g] = i;
        }
        if (i == n - 1) {
            for (int g = b + 1; g <= GRAPHS; ++g) gstart[g] = n;
        }
    }
    s[threadIdx.x] = v;
    __syncthreads();
    for (int off = 1; off < SCAN_B; off <<= 1) {
        int t = (threadIdx.x >= off) ? s[threadIdx.x - off] : 0;
        __syncthreads();
        s[threadIdx.x] += t;
        __syncthreads();
    }
    if (i < n) excl[i] = s[threadIdx.x] - v;
    if (threadIdx.x == SCAN_B - 1) blockSums[blockIdx.x] = s[SCAN_B - 1];
}

// ---------------- scan3 with inline block-sum scan (replaces scan2+scan3) ----------
__global__ void scan3_kernel(int* __restrict__ offs, const int* __restrict__ blockSums,
                             int n, int total, int nb) {
    __shared__ int s[SCAN_B];
    int t = threadIdx.x;
    int v = (t < nb) ? blockSums[t] : 0;
    s[t] = v;
    __syncthreads();
    for (int off = 1; off < SCAN_B; off <<= 1) {
        int x = (t >= off) ? s[t - off] : 0;
        __syncthreads();
        s[t] += x;
        __syncthreads();
    }
    int pre = (blockIdx.x == 0) ? 0 : s[blockIdx.x - 1];   // exclusive prefix of my block
    int i = blockIdx.x * SCAN_B + t;
    if (i < n) offs[i] += pre;
    if (i == 0) offs[n] = total;
}

// ---------------- scatter edges into CSR: NO atomics, single 4B write per edge ------
// entry = (src:16 | bf16(dinv[src]*w):16)
__global__ void scatter_kernel(const int* __restrict__ ei, const float* __restrict__ w,
                               const float* __restrict__ dinv, const int* __restrict__ offs,
                               const unsigned short* __restrict__ rank,
                               unsigned* __restrict__ csr, int E) {
    int e = blockIdx.x * blockDim.x + threadIdx.x;
    if (e >= E) return;
    int s = ei[e];
    int d = ei[E + e];
    unsigned v = ((unsigned)s << 16) | (unsigned)f2b(dinv[s] * w[e]);
    csr[offs[d] + (int)rank[e]] = v;
}

// ---------------- one hop: node-per-wave, 16 edges in flight, 16B gathers -----------
// 16-lane group g handles edges j+4g .. j+4g+3 -> 4 independent gather chains/group.
// Avg degree 12.5 -> most nodes finish in ONE iteration.
__global__ __launch_bounds__(256) void hop_kernel(const unsigned short* __restrict__ hin,
                                                  unsigned short* __restrict__ hout,
                                                  const int* __restrict__ offs,
                                                  const unsigned* __restrict__ csr,
                                                  const float* __restrict__ dinv, int n) {
    int lane = threadIdx.x & 63;
    int node = blockIdx.x * 4 + (threadIdx.x >> 6);
    if (node >= n) return;
    int g = lane >> 4, fl = lane & 15;
    int e0 = offs[node], e1 = offs[node + 1];
    float acc[8] = {};
    for (int j = e0; j < e1; j += 16) {
        int base = j + g * 4;
        int c0 = min(base + 0, e1 - 1), c1 = min(base + 1, e1 - 1);
        int c2 = min(base + 2, e1 - 1), c3 = min(base + 3, e1 - 1);
        unsigned ed0 = csr[c0], ed1 = csr[c1], ed2 = csr[c2], ed3 = csr[c3];
        float w0 = (base + 0 < e1) ? b2f((unsigned short)(ed0 & 0xffffu)) : 0.f;
        float w1 = (base + 1 < e1) ? b2f((unsigned short)(ed1 & 0xffffu)) : 0.f;
        float w2 = (base + 2 < e1) ? b2f((unsigned short)(ed2 & 0xffffu)) : 0.f;
        float w3 = (base + 3 < e1) ? b2f((unsigned short)(ed3 & 0xffffu)) : 0.f;
        short8 h0 = *(const short8*)(hin + (size_t)(ed0 >> 16) * 128 + fl * 8);
        short8 h1 = *(const short8*)(hin + (size_t)(ed1 >> 16) * 128 + fl * 8);
        short8 h2 = *(const short8*)(hin + (size_t)(ed2 >> 16) * 128 + fl * 8);
        short8 h3 = *(const short8*)(hin + (size_t)(ed3 >> 16) * 128 + fl * 8);
        #pragma unroll
        for (int k = 0; k < 8; ++k) {
            acc[k] += w0 * b2f((unsigned short)h0[k]) + w1 * b2f((unsigned short)h1[k]);
            acc[k] += w2 * b2f((unsigned short)h2[k]) + w3 * b2f((unsigned short)h3[k]);
        }
    }
    #pragma unroll
    for (int k = 0; k < 8; ++k) {
        acc[k] += __shfl_xor(acc[k], 16);
        acc[k] += __shfl_xor(acc[k], 32);
    }
    if (lane < 16) {
        float dd = dinv[node];
        short8 o;
        #pragma unroll
        for (int k = 0; k < 8; ++k) o[k] = (short)f2b(acc[k] * dd);
        *(short8*)(hout + (size_t)node * 128 + fl * 8) = o;
    }
}

// ---------------- fused GEMM: outb[N,128] = [y|h1|h2|h3] @ [W0;W1;W2;W3] + bias ------
__global__ __launch_bounds__(256) void gemm_kernel(const unsigned short* __restrict__ hcat,
                                                   const unsigned short* __restrict__ Wf,
                                                   const float* __restrict__ bias,
                                                   float* __restrict__ outb,
                                                   int M, size_t NF) {
    __shared__ unsigned short As[4][4096];   // 8 KB per wave, wave-private
    int lane = threadIdx.x & 63;
    int wid = threadIdx.x >> 6;
    int wr = wid & 1, wc = wid >> 1;
    int quad = lane >> 4, l15 = lane & 15;
    int row0 = blockIdx.x * 64;
    unsigned short* myA = As[wid];
    f32x4 acc[2][4] = {};

    for (int s = 0; s < 4; ++s) {
        const unsigned short* Aseg = hcat + (size_t)s * NF;
        short8 stg[8];
        #pragma unroll
        for (int i = 0; i < 8; ++i) {
            int flat = i * 64 + lane;
            int r = flat >> 4, c = flat & 15;
            stg[i] = *(const short8*)(Aseg + (size_t)(row0 + wr * 32 + r) * 128 + c * 8);
        }
        #pragma unroll
        for (int i = 0; i < 8; ++i) {
            int flat = i * 64 + lane;
            int r = flat >> 4, c = flat & 15;
            *(short8*)&myA[(r * 16 + (c ^ (r & 15))) * 8] = stg[i];
        }
        #pragma unroll
        for (int kb = 0; kb < 4; ++kb) {
            int swz = ((kb * 4 + quad) ^ l15) * 8;
            short8 a0 = *(short8*)&myA[l15 * 128 + swz];
            short8 a1 = *(short8*)&myA[(16 + l15) * 128 + swz];
            const unsigned short* bb = Wf + (size_t)(((s * 4 + kb) * 2 + wc) * 4) * 512 + lane * 8;
            short8 b0 = *(const short8*)(bb + 0 * 512);
            short8 b1 = *(const short8*)(bb + 1 * 512);
            short8 b2 = *(const short8*)(bb + 2 * 512);
            short8 b3 = *(const short8*)(bb + 3 * 512);
            acc[0][0] = __builtin_amdgcn_mfma_f32_16x16x32_bf16(a0, b0, acc[0][0], 0, 0, 0);
            acc[0][1] = __builtin_amdgcn_mfma_f32_16x16x32_bf16(a0, b1, acc[0][1], 0, 0, 0);
            acc[0][2] = __builtin_amdgcn_mfma_f32_16x16x32_bf16(a0, b2, acc[0][2], 0, 0, 0);
            acc[0][3] = __builtin_amdgcn_mfma_f32_16x16x32_bf16(a0, b3, acc[0][3], 0, 0, 0);
            acc[1][0] = __builtin_amdgcn_mfma_f32_16x16x32_bf16(a1, b0, acc[1][0], 0, 0, 0);
            acc[1][1] = __builtin_amdgcn_mfma_f32_16x16x32_bf16(a1, b1, acc[1][1], 0, 0, 0);
            acc[1][2] = __builtin_amdgcn_mfma_f32_16x16x32_bf16(a1, b2, acc[1][2], 0, 0, 0);
            acc[1][3] = __builtin_amdgcn_mfma_f32_16x16x32_bf16(a1, b3, acc[1][3], 0, 0, 0);
        }
    }

    #pragma unroll
    for (int mt = 0; mt < 2; ++mt) {
        #pragma unroll
        for (int r = 0; r < 4; ++r) {
            int row = row0 + wr * 32 + mt * 16 + quad * 4 + r;
            if (row < M) {
                #pragma unroll
                for (int nt = 0; nt < 4; ++nt) {
                    int col = wc * 64 + nt * 16 + l15;
                    outb[(size_t)row * 128 + col] = acc[mt][nt][r] + bias[col];
                }
            }
        }
    }
}

// ---------------- per-graph sums S1, S2 (parallel; sorted-batch flush trick) ----------
#define STAT_NODES 32
__global__ __launch_bounds__(256) void stats_kernel(const float* __restrict__ out,
                                                    const int* __restrict__ batch,
                                                    float* __restrict__ S1, float* __restrict__ S2,
                                                    int n) {
    int f = threadIdx.x & 127;
    int par = threadIdx.x >> 7;
    int base = blockIdx.x * STAT_NODES;
    int n1 = min(base + STAT_NODES, n);
    int i0 = base + par;
    if (i0 >= n1) return;
    float s1 = 0.f, s2 = 0.f;
    int curg = batch[i0];
    for (int i = i0; i < n1; i += 2) {
        int g = batch[i];
        if (g != curg) {
            atomicAdd(&S1[curg * F + f], s1);
            atomicAdd(&S2[curg * F + f], s2);
            s1 = 0.f; s2 = 0.f; curg = g;
        }
        float v = out[(size_t)i * F + f];
        s1 += v; s2 += v * v;
    }
    atomicAdd(&S1[curg * F + f], s1);
    atomicAdd(&S2[curg * F + f], s2);
}

// ---------------- finalize mean/var -> sm = s*mean, Ag = gnw * rsqrt(var+eps) --------
__global__ void finalize_kernel(const float* __restrict__ S1, const float* __restrict__ S2,
                                const int* __restrict__ gstart, const float* __restrict__ gnw,
                                const float* __restrict__ gms,
                                float* __restrict__ sm, float* __restrict__ Ag, int GF) {
    int i = blockIdx.x * blockDim.x + threadIdx.x;
    if (i >= GF) return;
    int f = i & (F - 1);
    int g = i >> 7;
    float c = fmaxf((float)(gstart[g + 1] - gstart[g]), 1.f);
    float mean = S1[i] / c;
    float e2 = S2[i] / c;
    float s = gms[f];
    float var = e2 - 2.f * s * mean * mean + s * s * mean * mean;
    sm[i] = s * mean;
    Ag[i] = gnw[f] * rsqrtf(var + GN_EPS);
}

// ---------------- fused normalize + relu + residual (y read as bf16 slice) ----------
__global__ void final_kernel(const ushort4* __restrict__ yb, const float4* __restrict__ out,
                             const int* __restrict__ batch, const float4* __restrict__ sm,
                             const float4* __restrict__ Ag, const float4* __restrict__ gnb,
                             float4* __restrict__ res, int n) {
    int idx = blockIdx.x * blockDim.x + threadIdx.x;
    if (idx >= n * 32) return;
    int node = idx >> 5;
    int q = idx & 31;
    int g = batch[node];
    float4 o = out[idx];
    ushort4 yv4 = yb[idx];
    float4 m = sm[g * 32 + q];
    float4 a = Ag[g * 32 + q];
    float4 b = gnb[q];
    float4 r;
    r.x = b2f(yv4.x) + fmaxf(0.f, (o.x - m.x) * a.x + b.x);
    r.y = b2f(yv4.y) + fmaxf(0.f, (o.y - m.y) * a.y + b.y);
    r.z = b2f(yv4.z) + fmaxf(0.f, (o.z - m.z) * a.z + b.z);
    r.w = b2f(yv4.w) + fmaxf(0.f, (o.w - m.w) * a.w + b.w);
    res[idx] = r;
}

extern "C" void kernel_launch(void* const* d_in, const int* in_sizes, int n_in,
                              void* d_out, int out_size, void* d_ws, size_t ws_size,
                              hipStream_t stream) {
    const float* y     = (const float*)d_in[0];
    const int*   ei    = (const int*)d_in[1];
    const float* ew    = (const float*)d_in[2];
    const int*   batch = (const int*)d_in[3];
    const float* tag_w = (const float*)d_in[4];
    const float* tag_b = (const float*)d_in[5];
    const float* gnw   = (const float*)d_in[6];
    const float* gnb   = (const float*)d_in[7];
    const float* gms   = (const float*)d_in[8];
    float* res = (float*)d_out;

    const int N = in_sizes[0] / F;
    const int E = in_sizes[1] / 2;
    const size_t NF = (size_t)N * F;

    // ---- workspace layout (zero-init region first, one memset) ----
    char* p = (char*)d_ws;
    unsigned long long* packed = (unsigned long long*)p; p += (size_t)N * 8;
    float* S1 = (float*)p;       p += (size_t)GRAPHS * F * 4;
    float* S2 = (float*)p;       p += (size_t)GRAPHS * F * 4;
    size_t zeroBytes = (size_t)(p - (char*)d_ws);
    int*   gstart = (int*)p;     p += 512;
    float* dinv = (float*)p;     p += (size_t)N * 4;
    int*   offs = (int*)p;       p += (size_t)(N + 4) * 4;
    int*   blockSums = (int*)p;  p += 4096;
    unsigned short* rank = (unsigned short*)p; p += ((size_t)E * 2 + 15) & ~15ull;
    unsigned* csr = (unsigned*)p; p += (size_t)E * 4;
    unsigned short* Wf = (unsigned short*)p; p += 4 * 128 * 128 * 2;
    unsigned short* hcat = (unsigned short*)p; p += NF * 2 * 4;   // 4 bf16 slices
    float* outb = (float*)p;     p += NF * 4;                      // right after hcat (OOB-read pad)
    float* sm = (float*)p;       p += (size_t)GRAPHS * F * 4;
    float* Ag = (float*)p;       p += (size_t)GRAPHS * F * 4;

    hipMemsetAsync(d_ws, 0, zeroBytes, stream);

    int eb = (E + 255) / 256;
    int sb = (N + SCAN_B - 1) / SCAN_B;
    int n4 = N * 32;
    int fb = (n4 + 255) / 256;
    int wb = (4 * 128 * 128) / 256;

    unsigned short* hs0 = hcat;
    unsigned short* hs1 = hcat + NF;
    unsigned short* hs2 = hcat + 2 * NF;
    unsigned short* hs3 = hcat + 3 * NF;

    prep_kernel<<<eb + fb + wb, 256, 0, stream>>>(ei, ew, packed, rank, E, eb,
                                                  (const float4*)y, (ushort4*)hs0, n4, fb,
                                                  tag_w, Wf);
    node_prep_kernel<<<sb, SCAN_B, 0, stream>>>(packed, dinv, batch, gstart, offs, blockSums, N);
    scan3_kernel<<<sb, SCAN_B, 0, stream>>>(offs, blockSums, N, E, sb);
    scatter_kernel<<<eb, 256, 0, stream>>>(ei, ew, dinv, offs, rank, csr, E);

    int hb = (N + 3) / 4;
    hop_kernel<<<hb, 256, 0, stream>>>(hs0, hs1, offs, csr, dinv, N);
    hop_kernel<<<hb, 256, 0, stream>>>(hs1, hs2, offs, csr, dinv, N);
    hop_kernel<<<hb, 256, 0, stream>>>(hs2, hs3, offs, csr, dinv, N);

    gemm_kernel<<<(N + 63) / 64, 256, 0, stream>>>(hcat, Wf, tag_b, outb, N, NF);

    stats_kernel<<<(N + STAT_NODES - 1) / STAT_NODES, 256, 0, stream>>>(outb, batch, S1, S2, N);
    finalize_kernel<<<(GRAPHS * F + 255) / 256, 256, 0, stream>>>(S1, S2, gstart, gnw, gms, sm, Ag, GRAPHS * F);
    final_kernel<<<(N * 32 + 255) / 256, 256, 0, stream>>>((const ushort4*)hs0, (const float4*)outb,
                                                           batch, (const float4*)sm, (const float4*)Ag,
                                                           (const float4*)gnb, (float4*)res, N);
}